// Round 1
// baseline (233.299 us; speedup 1.0000x reference)
//
#include <hip/hip_runtime.h>

// CausalSelfAttention: B=4, T=2048, C=1024, H=16, D=64
// Pipeline: cvt(x,w) -> qkv GEMM (scatter Q/K/V) -> V transpose -> flash attn -> proj GEMM

typedef unsigned short u16b;
typedef __bf16 bf16x8 __attribute__((ext_vector_type(8)));
typedef float f32x4 __attribute__((ext_vector_type(4)));
typedef unsigned short u16x4 __attribute__((ext_vector_type(4)));

#define AS1(p) ((const __attribute__((address_space(1))) void*)(p))
#define AS3(p) ((__attribute__((address_space(3))) void*)(p))
// global -> LDS direct copy, 16B per lane; LDS dest = wave-uniform base + lane*16
#define GLDS(g, l) __builtin_amdgcn_global_load_lds(AS1(g), AS3(l), 16, 0, 0)

__device__ __forceinline__ u16b bfr(float v) {  // f32 -> bf16 bits, RNE
  union { float f; unsigned u; } x; x.f = v;
  unsigned r = x.u + 0x7fffu + ((x.u >> 16) & 1u);
  return (u16b)(r >> 16);
}

// ---------------- x (fp32) -> bf16, vectorized ----------------
__global__ __launch_bounds__(256) void cvt_bf16_kernel(
    const float* __restrict__ src, u16b* __restrict__ dst, int n4) {
  int i = blockIdx.x * 256 + threadIdx.x;
  const int stride = gridDim.x * 256;
  for (; i < n4; i += stride) {
    const float4 v = reinterpret_cast<const float4*>(src)[i];
    u16x4 o;
    o[0] = bfr(v.x); o[1] = bfr(v.y); o[2] = bfr(v.z); o[3] = bfr(v.w);
    reinterpret_cast<u16x4*>(dst)[i] = o;
  }
}

// ---------------- weights: src[R][C] fp32 -> dst[C][R] bf16 (transpose) ----------------
__global__ __launch_bounds__(256) void transpose_cvt_kernel(
    const float* __restrict__ src, u16b* __restrict__ dst, int R, int C) {
  __shared__ u16b tile[64][72];
  const int nc = C >> 6;
  const int br = blockIdx.x / nc, bc = blockIdx.x % nc;
  const int r0 = br << 6, c0 = bc << 6;
  const int c = threadIdx.x & 63, r4 = threadIdx.x >> 6;
  #pragma unroll
  for (int i = 0; i < 16; ++i) {
    const int r = r4 + 4 * i;
    tile[r][c] = bfr(src[(size_t)(r0 + r) * C + c0 + c]);
  }
  __syncthreads();
  #pragma unroll
  for (int i = 0; i < 16; ++i) {
    const int rr = r4 + 4 * i;
    dst[(size_t)(c0 + rr) * R + r0 + c] = tile[c][rr];
  }
}

// ---------------- V [bh][2048][64] -> Vt [bh][64][2048] (bf16) ----------------
__global__ __launch_bounds__(256) void transpose_v_kernel(
    const u16b* __restrict__ V, u16b* __restrict__ Vt) {
  __shared__ u16b tile[64][72];
  const int bid = blockIdx.x;
  const int bh = bid >> 5, t0 = (bid & 31) << 6;
  const int c = threadIdx.x & 63, r4 = threadIdx.x >> 6;
  const u16b* src = V + ((size_t)bh * 2048 + t0) * 64;
  #pragma unroll
  for (int i = 0; i < 16; ++i) {
    const int t = r4 + 4 * i;
    tile[t][c] = src[(size_t)t * 64 + c];
  }
  __syncthreads();
  u16b* dst = Vt + (size_t)bh * 64 * 2048 + t0;
  #pragma unroll
  for (int i = 0; i < 16; ++i) {
    const int d = r4 + 4 * i;
    dst[(size_t)d * 2048 + c] = tile[c][d];
  }
}

// ---------------- 128x128 tile bf16 GEMM (m97 structure) ----------------
// C[M][N] = A[M][K] * Bt[N][K]^T + bias
// EPI==0: scatter into Q (scaled by 0.125), K, V as [B,H,T,D] bf16
// EPI==1: fp32 out [M][N]
template <int EPI>
__global__ __launch_bounds__(256, 2) void gemm128_kernel(
    const u16b* __restrict__ A, const u16b* __restrict__ Bt,
    const float* __restrict__ bias,
    u16b* __restrict__ oQ, u16b* __restrict__ oK, u16b* __restrict__ oV,
    float* __restrict__ oF, int M, int N, int K) {
  __shared__ u16b As[128 * 32];
  __shared__ u16b Bs[128 * 32];
  const int tid = threadIdx.x;
  const int wid = tid >> 6, lane = tid & 63;
  const int nb = N >> 7;
  const int brow = blockIdx.x / nb, bcol = blockIdx.x % nb;
  const int wr = (wid >> 1) << 6, wc = (wid & 1) << 6;

  f32x4 acc[4][4] = {};

  // staging: per wave, rows [wid*16, wid*16+16) (+64 in round 1); 4 lanes per 64B row
  const int ar = (wid << 4) + (lane >> 2);
  const int ac = (lane & 3) << 3;
  const u16b* Ab = A + (size_t)((brow << 7) + ar) * K + ac;
  const u16b* Bb = Bt + (size_t)((bcol << 7) + ar) * K + ac;
  const int fr = lane & 15;
  const int fk = (lane >> 4) << 3;

  for (int kk = 0; kk < K; kk += 32) {
    __syncthreads();
    GLDS(Ab + kk,                  (char*)As + wid * 1024);
    GLDS(Ab + (size_t)64 * K + kk, (char*)As + 4096 + wid * 1024);
    GLDS(Bb + kk,                  (char*)Bs + wid * 1024);
    GLDS(Bb + (size_t)64 * K + kk, (char*)Bs + 4096 + wid * 1024);
    __syncthreads();
    bf16x8 af[4], bfv[4];
    #pragma unroll
    for (int i = 0; i < 4; ++i)
      af[i] = *(const bf16x8*)&As[(wr + i * 16 + fr) * 32 + fk];
    #pragma unroll
    for (int j = 0; j < 4; ++j)
      bfv[j] = *(const bf16x8*)&Bs[(wc + j * 16 + fr) * 32 + fk];
    #pragma unroll
    for (int i = 0; i < 4; ++i)
      #pragma unroll
      for (int j = 0; j < 4; ++j)
        acc[i][j] = __builtin_amdgcn_mfma_f32_16x16x32_bf16(af[i], bfv[j], acc[i][j], 0, 0, 0);
  }

  const int fq = lane >> 4;
  #pragma unroll
  for (int j = 0; j < 4; ++j) {
    const int n0 = (bcol << 7) + wc + j * 16 + fr;
    const float bv = bias[n0];
    #pragma unroll
    for (int i = 0; i < 4; ++i) {
      #pragma unroll
      for (int r = 0; r < 4; ++r) {
        const int m0 = (brow << 7) + wr + i * 16 + fq * 4 + r;
        const float v = acc[i][j][r] + bv;
        if (EPI == 0) {
          const int sect = n0 >> 10, cc = n0 & 1023;
          const int h = cc >> 6, d = cc & 63;
          const int b = m0 >> 11, t = m0 & 2047;
          const size_t idx = ((size_t)((b << 4) + h) * 2048 + t) * 64 + d;
          if (sect == 0)      oQ[idx] = bfr(v * 0.125f);  // fold 1/sqrt(D)
          else if (sect == 1) oK[idx] = bfr(v);
          else                oV[idx] = bfr(v);
        } else {
          oF[(size_t)m0 * N + n0] = v;
        }
      }
    }
  }
}

// ---------------- flash attention ----------------
// grid = 32 qtiles * 64 bh; block = 4 waves; wave owns 16 q rows; KV tile = 64
// LDS tiles have 128B rows -> XOR chunk swizzle (chunk ^= row&7) with
// pre-swizzled global_load_lds SOURCE (linear dest) and swizzled reads.
__global__ __launch_bounds__(256, 2) void flash_kernel(
    const u16b* __restrict__ Q, const u16b* __restrict__ K,
    const u16b* __restrict__ Vt, u16b* __restrict__ O) {
  __shared__ u16b Ks[4096];  // [t(64)][d(64)] swizzled
  __shared__ u16b Vs[4096];  // [d(64)][t(64)] swizzled
  __shared__ u16b Ps[4096];  // per-wave [q(16)][t(64)] swizzled
  const int bid = blockIdx.x;
  const int bh = bid & 63;
  const int qt = 31 - (bid >> 6);  // heavy q-tiles dispatch first
  const int q0 = qt << 6;
  const int tid = threadIdx.x, wid = tid >> 6, lane = tid & 63;
  const int fr = lane & 15, fq = lane >> 4;
  const size_t baseQK = (size_t)bh * 2048 * 64;
  const size_t baseV = (size_t)bh * 64 * 2048;

  // Q fragments held in registers for whole kernel (A-operand layout)
  bf16x8 qf0, qf1;
  {
    const u16b* qp = Q + baseQK + (size_t)(q0 + wid * 16 + fr) * 64 + fq * 8;
    qf0 = *(const bf16x8*)(qp);
    qf1 = *(const bf16x8*)(qp + 32);
  }

  // staging lane positions: row = wid*8 + lane/8 (32 rows/round), chunk = lane&7
  const int srow = wid * 8 + (lane >> 3);
  const int sc = ((lane & 7) ^ (srow & 7)) << 3;  // pre-swizzled source chunk (elems)

  float m_run[4], l_run[4];
  f32x4 o_acc[4] = {};
  #pragma unroll
  for (int r = 0; r < 4; ++r) { m_run[r] = -3e38f; l_run[r] = 0.f; }

  for (int kt = 0; kt <= qt; ++kt) {
    const int k0 = kt << 6;
    __syncthreads();
    GLDS(K + baseQK + (size_t)(k0 + srow) * 64 + sc,       (char*)Ks + wid * 1024);
    GLDS(K + baseQK + (size_t)(k0 + 32 + srow) * 64 + sc,  (char*)Ks + 4096 + wid * 1024);
    GLDS(Vt + baseV + (size_t)srow * 2048 + k0 + sc,       (char*)Vs + wid * 1024);
    GLDS(Vt + baseV + (size_t)(32 + srow) * 2048 + k0 + sc,(char*)Vs + 4096 + wid * 1024);
    __syncthreads();

    // S = Q * K^T (16 q x 64 t per wave); C layout: row q = fq*4+r, col t = nt*16+fr
    f32x4 s[4];
    #pragma unroll
    for (int nt = 0; nt < 4; ++nt) {
      const int tl = nt * 16 + fr;
      const bf16x8 kf0 = *(const bf16x8*)((const char*)Ks + tl * 128 + ((fq)     ^ (tl & 7)) * 16);
      const bf16x8 kf1 = *(const bf16x8*)((const char*)Ks + tl * 128 + ((fq + 4) ^ (tl & 7)) * 16);
      f32x4 a = {};
      a = __builtin_amdgcn_mfma_f32_16x16x32_bf16(qf0, kf0, a, 0, 0, 0);
      a = __builtin_amdgcn_mfma_f32_16x16x32_bf16(qf1, kf1, a, 0, 0, 0);
      s[nt] = a;
    }

    if (kt == qt) {  // diagonal tile: causal mask
      #pragma unroll
      for (int nt = 0; nt < 4; ++nt) {
        const int tl = nt * 16 + fr;
        #pragma unroll
        for (int r = 0; r < 4; ++r) {
          const int ql = wid * 16 + fq * 4 + r;
          if (tl > ql) s[nt][r] = -3e38f;
        }
      }
    }

    // row max over 64 t: per-lane over nt, then shfl_xor across the 16-lane group
    float tm[4];
    #pragma unroll
    for (int r = 0; r < 4; ++r)
      tm[r] = fmaxf(fmaxf(s[0][r], s[1][r]), fmaxf(s[2][r], s[3][r]));
    #pragma unroll
    for (int off = 1; off < 16; off <<= 1) {
      #pragma unroll
      for (int r = 0; r < 4; ++r)
        tm[r] = fmaxf(tm[r], __shfl_xor(tm[r], off));
    }

    float ps[4];
    #pragma unroll
    for (int r = 0; r < 4; ++r) {
      const float mnew = fmaxf(m_run[r], tm[r]);
      ps[r] = __expf(m_run[r] - mnew);
      m_run[r] = mnew;
    }

    // P = exp(S - m), write bf16 to per-wave LDS (swizzled), accumulate row sums
    char* pbase = (char*)Ps + wid * 2048;
    float rsum[4] = {0.f, 0.f, 0.f, 0.f};
    #pragma unroll
    for (int nt = 0; nt < 4; ++nt) {
      const int tl = nt * 16 + fr;
      const int ch = tl >> 3;
      #pragma unroll
      for (int r = 0; r < 4; ++r) {
        const float p = __expf(s[nt][r] - m_run[r]);
        rsum[r] += p;
        const int q = fq * 4 + r;
        *(u16b*)(pbase + q * 128 + ((ch ^ (q & 7)) * 16) + (tl & 7) * 2) = bfr(p);
      }
    }

    #pragma unroll
    for (int r = 0; r < 4; ++r) {
      float v = rsum[r];
      #pragma unroll
      for (int off = 1; off < 16; off <<= 1) v += __shfl_xor(v, off);
      l_run[r] = l_run[r] * ps[r] + v;
      #pragma unroll
      for (int dt = 0; dt < 4; ++dt) o_acc[dt][r] *= ps[r];
    }

    // PV: A = P (own-wave LDS region, same-wave RAW -> compiler waits, no barrier)
    const bf16x8 pf0 = *(const bf16x8*)(pbase + fr * 128 + ((fq)     ^ (fr & 7)) * 16);
    const bf16x8 pf1 = *(const bf16x8*)(pbase + fr * 128 + ((fq + 4) ^ (fr & 7)) * 16);
    #pragma unroll
    for (int dt = 0; dt < 4; ++dt) {
      const int d = dt * 16 + fr;
      const bf16x8 v0 = *(const bf16x8*)((const char*)Vs + d * 128 + ((fq)     ^ (d & 7)) * 16);
      const bf16x8 v1 = *(const bf16x8*)((const char*)Vs + d * 128 + ((fq + 4) ^ (d & 7)) * 16);
      o_acc[dt] = __builtin_amdgcn_mfma_f32_16x16x32_bf16(pf0, v0, o_acc[dt], 0, 0, 0);
      o_acc[dt] = __builtin_amdgcn_mfma_f32_16x16x32_bf16(pf1, v1, o_acc[dt], 0, 0, 0);
    }
  }

  // epilogue: O[b, t=q, h*64+d] bf16, row-major [B*T][C]
  const int b = bh >> 4, h = bh & 15;
  #pragma unroll
  for (int r = 0; r < 4; ++r) {
    const int q = q0 + wid * 16 + fq * 4 + r;
    const float inv = 1.0f / l_run[r];
    const size_t row = (size_t)(b * 2048 + q) * 1024 + h * 64;
    #pragma unroll
    for (int dt = 0; dt < 4; ++dt)
      O[row + dt * 16 + fr] = bfr(o_acc[dt][r] * inv);
  }
}

extern "C" void kernel_launch(void* const* d_in, const int* in_sizes, int n_in,
                              void* d_out, int out_size, void* d_ws, size_t ws_size,
                              hipStream_t stream) {
  const float* x      = (const float*)d_in[0];
  const float* w_attn = (const float*)d_in[1];
  const float* b_attn = (const float*)d_in[2];
  const float* w_proj = (const float*)d_in[3];
  const float* b_proj = (const float*)d_in[4];
  float* out = (float*)d_out;
  char* ws = (char*)d_ws;

  // workspace layout (bytes)
  u16b* xb  = (u16b*)(ws + 0);          // [8192][1024] bf16 x; later reused as attn_out
  u16b* waT = (u16b*)(ws + 16777216);   // [3072][1024] w_attn^T bf16
  u16b* wpT = (u16b*)(ws + 23068672);   // [1024][1024] w_proj^T bf16
  u16b* Qb  = (u16b*)(ws + 25165824);   // [64 bh][2048][64]
  u16b* Kb  = (u16b*)(ws + 41943040);
  u16b* Vb  = (u16b*)(ws + 58720256);
  u16b* Vtb = (u16b*)(ws + 75497472);   // [64 bh][64][2048]
  u16b* attn = xb;                      // alias: xb dead after qkv GEMM

  cvt_bf16_kernel<<<2048, 256, 0, stream>>>(x, xb, (8192 * 1024) / 4);
  transpose_cvt_kernel<<<16 * 48, 256, 0, stream>>>(w_attn, waT, 1024, 3072);
  transpose_cvt_kernel<<<16 * 16, 256, 0, stream>>>(w_proj, wpT, 1024, 1024);
  gemm128_kernel<0><<<64 * 24, 256, 0, stream>>>(xb, waT, b_attn, Qb, Kb, Vb, nullptr,
                                                 8192, 3072, 1024);
  transpose_v_kernel<<<64 * 32, 256, 0, stream>>>(Vb, Vtb);
  flash_kernel<<<64 * 32, 256, 0, stream>>>(Qb, Kb, Vtb, attn);
  gemm128_kernel<1><<<64 * 8, 256, 0, stream>>>(attn, wpT, b_proj, nullptr, nullptr, nullptr,
                                                out, 8192, 1024, 1024);
}

// Round 2
// 225.771 us; speedup vs baseline: 1.0333x; 1.0333x over previous
//
#include <hip/hip_runtime.h>

// CausalSelfAttention: B=4, T=2048, C=1024, H=16, D=64
// Pipeline: cvt(x,w) -> qkv GEMM (scatter Q/K/V) -> V transpose -> flash attn (swapped 32x32) -> proj GEMM

typedef unsigned short u16b;
typedef __bf16 bf16x8 __attribute__((ext_vector_type(8)));
typedef float f32x4 __attribute__((ext_vector_type(4)));
typedef float f32x16 __attribute__((ext_vector_type(16)));
typedef unsigned short u16x4 __attribute__((ext_vector_type(4)));

#define AS1(p) ((const __attribute__((address_space(1))) void*)(p))
#define AS3(p) ((__attribute__((address_space(3))) void*)(p))
#define GLDS(g, l) __builtin_amdgcn_global_load_lds(AS1(g), AS3(l), 16, 0, 0)

__device__ __forceinline__ u16b bfr(float v) {  // f32 -> bf16 bits, RNE
  union { float f; unsigned u; } x; x.f = v;
  unsigned r = x.u + 0x7fffu + ((x.u >> 16) & 1u);
  return (u16b)(r >> 16);
}

__device__ __forceinline__ unsigned pk2(float lo, float hi) {  // pack 2 f32 -> 2 bf16 in u32
  union { __bf16 h[2]; unsigned u; } t;
  t.h[0] = (__bf16)lo; t.h[1] = (__bf16)hi;
  return t.u;
}

// ---------------- x (fp32) -> bf16, vectorized ----------------
__global__ __launch_bounds__(256) void cvt_bf16_kernel(
    const float* __restrict__ src, u16b* __restrict__ dst, int n4) {
  int i = blockIdx.x * 256 + threadIdx.x;
  const int stride = gridDim.x * 256;
  for (; i < n4; i += stride) {
    const float4 v = reinterpret_cast<const float4*>(src)[i];
    u16x4 o;
    o[0] = bfr(v.x); o[1] = bfr(v.y); o[2] = bfr(v.z); o[3] = bfr(v.w);
    reinterpret_cast<u16x4*>(dst)[i] = o;
  }
}

// ---------------- weights: src[R][C] fp32 -> dst[C][R] bf16 (transpose) ----------------
__global__ __launch_bounds__(256) void transpose_cvt_kernel(
    const float* __restrict__ src, u16b* __restrict__ dst, int R, int C) {
  __shared__ u16b tile[64][72];
  const int nc = C >> 6;
  const int br = blockIdx.x / nc, bc = blockIdx.x % nc;
  const int r0 = br << 6, c0 = bc << 6;
  const int c = threadIdx.x & 63, r4 = threadIdx.x >> 6;
  #pragma unroll
  for (int i = 0; i < 16; ++i) {
    const int r = r4 + 4 * i;
    tile[r][c] = bfr(src[(size_t)(r0 + r) * C + c0 + c]);
  }
  __syncthreads();
  #pragma unroll
  for (int i = 0; i < 16; ++i) {
    const int rr = r4 + 4 * i;
    dst[(size_t)(c0 + rr) * R + r0 + c] = tile[c][rr];
  }
}

// ---------------- V [bh][2048][64] -> Vt [bh][64][2048] (bf16) ----------------
__global__ __launch_bounds__(256) void transpose_v_kernel(
    const u16b* __restrict__ V, u16b* __restrict__ Vt) {
  __shared__ u16b tile[64][72];
  const int bid = blockIdx.x;
  const int bh = bid >> 5, t0 = (bid & 31) << 6;
  const int c = threadIdx.x & 63, r4 = threadIdx.x >> 6;
  const u16b* src = V + ((size_t)bh * 2048 + t0) * 64;
  #pragma unroll
  for (int i = 0; i < 16; ++i) {
    const int t = r4 + 4 * i;
    tile[t][c] = src[(size_t)t * 64 + c];
  }
  __syncthreads();
  u16b* dst = Vt + (size_t)bh * 64 * 2048 + t0;
  #pragma unroll
  for (int i = 0; i < 16; ++i) {
    const int d = r4 + 4 * i;
    dst[(size_t)d * 2048 + c] = tile[c][d];
  }
}

// ---------------- 128x128 tile bf16 GEMM (m97 structure) ----------------
template <int EPI>
__global__ __launch_bounds__(256, 2) void gemm128_kernel(
    const u16b* __restrict__ A, const u16b* __restrict__ Bt,
    const float* __restrict__ bias,
    u16b* __restrict__ oQ, u16b* __restrict__ oK, u16b* __restrict__ oV,
    float* __restrict__ oF, int M, int N, int K) {
  __shared__ u16b As[128 * 32];
  __shared__ u16b Bs[128 * 32];
  const int tid = threadIdx.x;
  const int wid = tid >> 6, lane = tid & 63;
  const int nb = N >> 7;
  const int brow = blockIdx.x / nb, bcol = blockIdx.x % nb;
  const int wr = (wid >> 1) << 6, wc = (wid & 1) << 6;

  f32x4 acc[4][4] = {};

  const int ar = (wid << 4) + (lane >> 2);
  const int ac = (lane & 3) << 3;
  const u16b* Ab = A + (size_t)((brow << 7) + ar) * K + ac;
  const u16b* Bb = Bt + (size_t)((bcol << 7) + ar) * K + ac;
  const int fr = lane & 15;
  const int fk = (lane >> 4) << 3;

  for (int kk = 0; kk < K; kk += 32) {
    __syncthreads();
    GLDS(Ab + kk,                  (char*)As + wid * 1024);
    GLDS(Ab + (size_t)64 * K + kk, (char*)As + 4096 + wid * 1024);
    GLDS(Bb + kk,                  (char*)Bs + wid * 1024);
    GLDS(Bb + (size_t)64 * K + kk, (char*)Bs + 4096 + wid * 1024);
    __syncthreads();
    bf16x8 af[4], bfv[4];
    #pragma unroll
    for (int i = 0; i < 4; ++i)
      af[i] = *(const bf16x8*)&As[(wr + i * 16 + fr) * 32 + fk];
    #pragma unroll
    for (int j = 0; j < 4; ++j)
      bfv[j] = *(const bf16x8*)&Bs[(wc + j * 16 + fr) * 32 + fk];
    #pragma unroll
    for (int i = 0; i < 4; ++i)
      #pragma unroll
      for (int j = 0; j < 4; ++j)
        acc[i][j] = __builtin_amdgcn_mfma_f32_16x16x32_bf16(af[i], bfv[j], acc[i][j], 0, 0, 0);
  }

  const int fq = lane >> 4;
  #pragma unroll
  for (int j = 0; j < 4; ++j) {
    const int n0 = (bcol << 7) + wc + j * 16 + fr;
    const float bv = bias[n0];
    #pragma unroll
    for (int i = 0; i < 4; ++i) {
      #pragma unroll
      for (int r = 0; r < 4; ++r) {
        const int m0 = (brow << 7) + wr + i * 16 + fq * 4 + r;
        const float v = acc[i][j][r] + bv;
        if (EPI == 0) {
          const int sect = n0 >> 10, cc = n0 & 1023;
          const int h = cc >> 6, d = cc & 63;
          const int b = m0 >> 11, t = m0 & 2047;
          const size_t idx = ((size_t)((b << 4) + h) * 2048 + t) * 64 + d;
          // Q pre-scaled by 1/sqrt(D) * log2(e) so flash uses exp2 directly
          if (sect == 0)      oQ[idx] = bfr(v * 0.1803368801f);
          else if (sect == 1) oK[idx] = bfr(v);
          else                oV[idx] = bfr(v);
        } else {
          oF[(size_t)m0 * N + n0] = v;
        }
      }
    }
  }
}

// ---------------- flash attention, swapped-QK^T 32x32 structure ----------------
// 4 waves/block, 32 q-rows/wave (128/block), KVBLK=64, grid = 16 qtiles * 64 bh.
// S^T = mfma(K, Q): C col = lane&31 = q  -> softmax lane-local.
// O^T = mfma(V^T, P): C col = q again    -> rescale/normalize lane-local.
// P redistribution: pk2 pairs + v_permlane32_swap (T12).
__global__ __launch_bounds__(256, 3) void flash_kernel(
    const u16b* __restrict__ Q, const u16b* __restrict__ K,
    const u16b* __restrict__ Vt, u16b* __restrict__ O) {
  __shared__ u16b smem[8192];  // bytes 0..8191: Ks[64][64]; 8192..16383: Vs[64][64]
  const int bid = blockIdx.x;
  const int bh = bid >> 4;
  const int pid = bid & 15;
  const int g = (pid & 1) ? (pid >> 1) : (15 - (pid >> 1));  // heavy/light pairing
  const int q0 = g << 7;
  const int tid = threadIdx.x, wid = tid >> 6, lane = tid & 63;
  const int ln31 = lane & 31, hi = lane >> 5;
  const int q0w = q0 + wid * 32;
  const size_t baseQK = (size_t)bh * 2048 * 64;
  const size_t baseV = (size_t)bh * 64 * 2048;

  // Q fragments (B-operand): qf[kk] = Q[q0w+ln31][16*kk + 8*hi .. +8]
  bf16x8 qf[4];
  {
    const u16b* qp = Q + baseQK + (size_t)(q0w + ln31) * 64 + hi * 8;
    #pragma unroll
    for (int kk = 0; kk < 4; ++kk) qf[kk] = *(const bf16x8*)(qp + kk * 16);
  }

  // staging: row = wid*8 + lane/8, source chunk pre-swizzled (rule #21)
  const int srow = wid * 8 + (lane >> 3);
  const int sc = ((lane & 7) ^ (srow & 7)) << 3;

  const int NT = 2 * g + 2;       // kv tiles this block stages
  const int LT = q0w >> 6;        // last kv tile this wave computes

  float m_run = -3e38f, l_run = 0.f;
  f32x16 oa0 = {}, oa1 = {};      // O^T[d=32*t+crow(r,hi)][q=ln31]

  for (int kt = 0; kt < NT; ++kt) {
    const int k0 = kt << 6;
    __syncthreads();
    GLDS(K + baseQK + (size_t)(k0 + srow) * 64 + sc,        (char*)smem + wid * 1024);
    GLDS(K + baseQK + (size_t)(k0 + 32 + srow) * 64 + sc,   (char*)smem + 4096 + wid * 1024);
    GLDS(Vt + baseV + (size_t)srow * 2048 + k0 + sc,        (char*)smem + 8192 + wid * 1024);
    GLDS(Vt + baseV + (size_t)(32 + srow) * 2048 + k0 + sc, (char*)smem + 12288 + wid * 1024);
    __syncthreads();
    if (kt > LT) continue;  // barrier-only iteration (stages for other waves)

    const bool dodiag = (kt == LT);
    const bool do1 = (k0 + 32 <= q0w + 31);  // kv subtile 1 has any unmasked?

    // ---- QK^T (swapped): s[t] = S^T[kv=32t+crow][q=ln31], log2-domain ----
    f32x16 s0 = {}, s1 = {};
    __builtin_amdgcn_s_setprio(1);
    #pragma unroll
    for (int kk = 0; kk < 4; ++kk) {
      const int ch = ((2 * kk + hi) ^ (ln31 & 7));
      const bf16x8 kf = *(const bf16x8*)((const char*)smem + ln31 * 128 + ch * 16);
      s0 = __builtin_amdgcn_mfma_f32_32x32x16_bf16(kf, qf[kk], s0, 0, 0, 0);
    }
    if (do1) {
      #pragma unroll
      for (int kk = 0; kk < 4; ++kk) {
        const int row = 32 + ln31;
        const int ch = ((2 * kk + hi) ^ (row & 7));
        const bf16x8 kf = *(const bf16x8*)((const char*)smem + row * 128 + ch * 16);
        s1 = __builtin_amdgcn_mfma_f32_32x32x16_bf16(kf, qf[kk], s1, 0, 0, 0);
      }
    }
    __builtin_amdgcn_s_setprio(0);

    if (dodiag) {  // causal mask: kv > q -> -inf
      const int q = q0w + ln31;
      #pragma unroll
      for (int r = 0; r < 16; ++r) {
        const int kvr = k0 + (r & 3) + 8 * (r >> 2) + 4 * hi;
        if (kvr > q) s0[r] = -3e38f;
        if (kvr + 32 > q) s1[r] = -3e38f;
      }
    }

    // ---- online softmax, lane-local (lane owns row q=ln31; partner holds other 32 kv) ----
    float tm = s0[0];
    #pragma unroll
    for (int r = 1; r < 16; ++r) tm = fmaxf(tm, s0[r]);
    if (do1) {
      #pragma unroll
      for (int r = 0; r < 16; ++r) tm = fmaxf(tm, s1[r]);
    }
    tm = fmaxf(tm, __shfl_xor(tm, 32));
    const float mnew = fmaxf(m_run, tm);
    const float scale = __builtin_amdgcn_exp2f(m_run - mnew);
    m_run = mnew;
    float rs = 0.f;
    #pragma unroll
    for (int r = 0; r < 16; ++r) { s0[r] = __builtin_amdgcn_exp2f(s0[r] - mnew); rs += s0[r]; }
    if (do1) {
      #pragma unroll
      for (int r = 0; r < 16; ++r) { s1[r] = __builtin_amdgcn_exp2f(s1[r] - mnew); rs += s1[r]; }
    }
    rs += __shfl_xor(rs, 32);
    l_run = l_run * scale + rs;
    #pragma unroll
    for (int r = 0; r < 16; ++r) { oa0[r] *= scale; oa1[r] *= scale; }

    // ---- P -> bf16 B-fragments via cvt_pk + permlane32_swap (T12) ----
    // slice sl covers kv [16sl,16sl+16); word j of lane (q,hi) = kv {16sl+8hi+2j, +2j+1}
    unsigned w[16];
#define MKPA(W0, W1, W2, W3, P0, P1, P2, P3, P4, P5, P6, P7)                 \
    {                                                                         \
      unsigned a0 = pk2(P0, P1), a1 = pk2(P2, P3);                            \
      unsigned b0 = pk2(P4, P5), b1 = pk2(P6, P7);                            \
      auto r0 = __builtin_amdgcn_permlane32_swap(a0, b0, false, false);       \
      auto r1 = __builtin_amdgcn_permlane32_swap(a1, b1, false, false);       \
      unsigned o0[2], o1[2];                                                  \
      __builtin_memcpy(o0, &r0, 8); __builtin_memcpy(o1, &r1, 8);             \
      W0 = o0[0]; W2 = o0[1]; W1 = o1[0]; W3 = o1[1];                         \
    }
    MKPA(w[0], w[1], w[2], w[3],    s0[0], s0[1], s0[2], s0[3], s0[4], s0[5], s0[6], s0[7]);
    MKPA(w[4], w[5], w[6], w[7],    s0[8], s0[9], s0[10], s0[11], s0[12], s0[13], s0[14], s0[15]);
    if (do1) {
      MKPA(w[8], w[9], w[10], w[11],   s1[0], s1[1], s1[2], s1[3], s1[4], s1[5], s1[6], s1[7]);
      MKPA(w[12], w[13], w[14], w[15], s1[8], s1[9], s1[10], s1[11], s1[12], s1[13], s1[14], s1[15]);
    }
#undef MKPA

    // ---- PV (swapped): oa[t] += mfma(V^T frag, P frag) ----
    union WB { unsigned u[4]; bf16x8 v; };
    __builtin_amdgcn_s_setprio(1);
    #pragma unroll
    for (int sl = 0; sl < 2; ++sl) {
      WB pb; pb.u[0] = w[sl * 4]; pb.u[1] = w[sl * 4 + 1];
      pb.u[2] = w[sl * 4 + 2]; pb.u[3] = w[sl * 4 + 3];
      const int ch0 = ((2 * sl + hi) ^ (ln31 & 7));
      const bf16x8 vf0 = *(const bf16x8*)((const char*)smem + 8192 + ln31 * 128 + ch0 * 16);
      oa0 = __builtin_amdgcn_mfma_f32_32x32x16_bf16(vf0, pb.v, oa0, 0, 0, 0);
      const int row1 = 32 + ln31;
      const int ch1 = ((2 * sl + hi) ^ (row1 & 7));
      const bf16x8 vf1 = *(const bf16x8*)((const char*)smem + 8192 + row1 * 128 + ch1 * 16);
      oa1 = __builtin_amdgcn_mfma_f32_32x32x16_bf16(vf1, pb.v, oa1, 0, 0, 0);
    }
    if (do1) {
      #pragma unroll
      for (int sl = 2; sl < 4; ++sl) {
        WB pb; pb.u[0] = w[sl * 4]; pb.u[1] = w[sl * 4 + 1];
        pb.u[2] = w[sl * 4 + 2]; pb.u[3] = w[sl * 4 + 3];
        const int ch0 = ((2 * sl + hi) ^ (ln31 & 7));
        const bf16x8 vf0 = *(const bf16x8*)((const char*)smem + 8192 + ln31 * 128 + ch0 * 16);
        oa0 = __builtin_amdgcn_mfma_f32_32x32x16_bf16(vf0, pb.v, oa0, 0, 0, 0);
        const int row1 = 32 + ln31;
        const int ch1 = ((2 * sl + hi) ^ (row1 & 7));
        const bf16x8 vf1 = *(const bf16x8*)((const char*)smem + 8192 + row1 * 128 + ch1 * 16);
        oa1 = __builtin_amdgcn_mfma_f32_32x32x16_bf16(vf1, pb.v, oa1, 0, 0, 0);
      }
    }
    __builtin_amdgcn_s_setprio(0);
  }

  // ---- epilogue: lane owns output row q = q0w+ln31; d = 32t + 8rq + 4hi + j ----
  const int b = bh >> 4, h = bh & 15;
  const float inv = 1.0f / l_run;
  const int q = q0w + ln31;
  u16b* orow = O + (size_t)(b * 2048 + q) * 1024 + h * 64;
  #pragma unroll
  for (int rq = 0; rq < 4; ++rq) {
    u16x4 v0, v1;
    #pragma unroll
    for (int j = 0; j < 4; ++j) {
      v0[j] = bfr(oa0[4 * rq + j] * inv);
      v1[j] = bfr(oa1[4 * rq + j] * inv);
    }
    const int d0 = 8 * rq + 4 * hi;
    *(u16x4*)(orow + d0) = v0;
    *(u16x4*)(orow + 32 + d0) = v1;
  }
}

extern "C" void kernel_launch(void* const* d_in, const int* in_sizes, int n_in,
                              void* d_out, int out_size, void* d_ws, size_t ws_size,
                              hipStream_t stream) {
  const float* x      = (const float*)d_in[0];
  const float* w_attn = (const float*)d_in[1];
  const float* b_attn = (const float*)d_in[2];
  const float* w_proj = (const float*)d_in[3];
  const float* b_proj = (const float*)d_in[4];
  float* out = (float*)d_out;
  char* ws = (char*)d_ws;

  u16b* xb  = (u16b*)(ws + 0);          // [8192][1024] bf16 x; later reused as attn_out
  u16b* waT = (u16b*)(ws + 16777216);   // [3072][1024] w_attn^T bf16
  u16b* wpT = (u16b*)(ws + 23068672);   // [1024][1024] w_proj^T bf16
  u16b* Qb  = (u16b*)(ws + 25165824);   // [64 bh][2048][64]
  u16b* Kb  = (u16b*)(ws + 41943040);
  u16b* Vb  = (u16b*)(ws + 58720256);
  u16b* Vtb = (u16b*)(ws + 75497472);   // [64 bh][64][2048]
  u16b* attn = xb;

  cvt_bf16_kernel<<<2048, 256, 0, stream>>>(x, xb, (8192 * 1024) / 4);
  transpose_cvt_kernel<<<16 * 48, 256, 0, stream>>>(w_attn, waT, 1024, 3072);
  transpose_cvt_kernel<<<16 * 16, 256, 0, stream>>>(w_proj, wpT, 1024, 1024);
  gemm128_kernel<0><<<64 * 24, 256, 0, stream>>>(xb, waT, b_attn, Qb, Kb, Vb, nullptr,
                                                 8192, 3072, 1024);
  transpose_v_kernel<<<64 * 32, 256, 0, stream>>>(Vb, Vtb);
  flash_kernel<<<1024, 256, 0, stream>>>(Qb, Kb, Vtb, attn);
  gemm128_kernel<1><<<64 * 8, 256, 0, stream>>>(attn, wpT, b_proj, nullptr, nullptr, nullptr,
                                                out, 8192, 1024, 1024);
}

// Round 3
// 197.133 us; speedup vs baseline: 1.1835x; 1.1453x over previous
//
#include <hip/hip_runtime.h>

// CausalSelfAttention: B=4, T=2048, C=1024, H=16, D=64
// Pipeline: cvt(x,w) -> qkv GEMM (scatter Q/K/V) -> V transpose -> flash attn (swapped 32x32,
//           paired-balanced blocks, dbuf counted-vmcnt staging) -> proj GEMM

typedef unsigned short u16b;
typedef __bf16 bf16x8 __attribute__((ext_vector_type(8)));
typedef float f32x4 __attribute__((ext_vector_type(4)));
typedef float f32x16 __attribute__((ext_vector_type(16)));
typedef unsigned short u16x4 __attribute__((ext_vector_type(4)));

#define AS1(p) ((const __attribute__((address_space(1))) void*)(p))
#define AS3(p) ((__attribute__((address_space(3))) void*)(p))
#define GLDS(g, l) __builtin_amdgcn_global_load_lds(AS1(g), AS3(l), 16, 0, 0)

__device__ __forceinline__ u16b bfr(float v) {  // f32 -> bf16 bits, RNE
  union { float f; unsigned u; } x; x.f = v;
  unsigned r = x.u + 0x7fffu + ((x.u >> 16) & 1u);
  return (u16b)(r >> 16);
}

__device__ __forceinline__ unsigned pk2(float lo, float hi) {  // pack 2 f32 -> 2 bf16 in u32
  union { __bf16 h[2]; unsigned u; } t;
  t.h[0] = (__bf16)lo; t.h[1] = (__bf16)hi;
  return t.u;
}

// ---------------- x (fp32) -> bf16, vectorized ----------------
__global__ __launch_bounds__(256) void cvt_bf16_kernel(
    const float* __restrict__ src, u16b* __restrict__ dst, int n4) {
  int i = blockIdx.x * 256 + threadIdx.x;
  const int stride = gridDim.x * 256;
  for (; i < n4; i += stride) {
    const float4 v = reinterpret_cast<const float4*>(src)[i];
    u16x4 o;
    o[0] = bfr(v.x); o[1] = bfr(v.y); o[2] = bfr(v.z); o[3] = bfr(v.w);
    reinterpret_cast<u16x4*>(dst)[i] = o;
  }
}

// ---------------- weights: src[R][C] fp32 -> dst[C][R] bf16 (transpose) ----------------
__global__ __launch_bounds__(256) void transpose_cvt_kernel(
    const float* __restrict__ src, u16b* __restrict__ dst, int R, int C) {
  __shared__ u16b tile[64][72];
  const int nc = C >> 6;
  const int br = blockIdx.x / nc, bc = blockIdx.x % nc;
  const int r0 = br << 6, c0 = bc << 6;
  const int c = threadIdx.x & 63, r4 = threadIdx.x >> 6;
  #pragma unroll
  for (int i = 0; i < 16; ++i) {
    const int r = r4 + 4 * i;
    tile[r][c] = bfr(src[(size_t)(r0 + r) * C + c0 + c]);
  }
  __syncthreads();
  #pragma unroll
  for (int i = 0; i < 16; ++i) {
    const int rr = r4 + 4 * i;
    dst[(size_t)(c0 + rr) * R + r0 + c] = tile[c][rr];
  }
}

// ---------------- V [bh][2048][64] -> Vt [bh][64][2048] (bf16) ----------------
__global__ __launch_bounds__(256) void transpose_v_kernel(
    const u16b* __restrict__ V, u16b* __restrict__ Vt) {
  __shared__ u16b tile[64][72];
  const int bid = blockIdx.x;
  const int bh = bid >> 5, t0 = (bid & 31) << 6;
  const int c = threadIdx.x & 63, r4 = threadIdx.x >> 6;
  const u16b* src = V + ((size_t)bh * 2048 + t0) * 64;
  #pragma unroll
  for (int i = 0; i < 16; ++i) {
    const int t = r4 + 4 * i;
    tile[t][c] = src[(size_t)t * 64 + c];
  }
  __syncthreads();
  u16b* dst = Vt + (size_t)bh * 64 * 2048 + t0;
  #pragma unroll
  for (int i = 0; i < 16; ++i) {
    const int d = r4 + 4 * i;
    dst[(size_t)d * 2048 + c] = tile[c][d];
  }
}

// ---------------- 128x128 tile bf16 GEMM (m97 structure) ----------------
template <int EPI>
__global__ __launch_bounds__(256, 2) void gemm128_kernel(
    const u16b* __restrict__ A, const u16b* __restrict__ Bt,
    const float* __restrict__ bias,
    u16b* __restrict__ oQ, u16b* __restrict__ oK, u16b* __restrict__ oV,
    float* __restrict__ oF, int M, int N, int K) {
  __shared__ u16b As[128 * 32];
  __shared__ u16b Bs[128 * 32];
  const int tid = threadIdx.x;
  const int wid = tid >> 6, lane = tid & 63;
  const int nb = N >> 7;
  const int brow = blockIdx.x / nb, bcol = blockIdx.x % nb;
  const int wr = (wid >> 1) << 6, wc = (wid & 1) << 6;

  f32x4 acc[4][4] = {};

  const int ar = (wid << 4) + (lane >> 2);
  const int ac = (lane & 3) << 3;
  const u16b* Ab = A + (size_t)((brow << 7) + ar) * K + ac;
  const u16b* Bb = Bt + (size_t)((bcol << 7) + ar) * K + ac;
  const int fr = lane & 15;
  const int fk = (lane >> 4) << 3;

  for (int kk = 0; kk < K; kk += 32) {
    __syncthreads();
    GLDS(Ab + kk,                  (char*)As + wid * 1024);
    GLDS(Ab + (size_t)64 * K + kk, (char*)As + 4096 + wid * 1024);
    GLDS(Bb + kk,                  (char*)Bs + wid * 1024);
    GLDS(Bb + (size_t)64 * K + kk, (char*)Bs + 4096 + wid * 1024);
    __syncthreads();
    bf16x8 af[4], bfv[4];
    #pragma unroll
    for (int i = 0; i < 4; ++i)
      af[i] = *(const bf16x8*)&As[(wr + i * 16 + fr) * 32 + fk];
    #pragma unroll
    for (int j = 0; j < 4; ++j)
      bfv[j] = *(const bf16x8*)&Bs[(wc + j * 16 + fr) * 32 + fk];
    #pragma unroll
    for (int i = 0; i < 4; ++i)
      #pragma unroll
      for (int j = 0; j < 4; ++j)
        acc[i][j] = __builtin_amdgcn_mfma_f32_16x16x32_bf16(af[i], bfv[j], acc[i][j], 0, 0, 0);
  }

  const int fq = lane >> 4;
  #pragma unroll
  for (int j = 0; j < 4; ++j) {
    const int n0 = (bcol << 7) + wc + j * 16 + fr;
    const float bv = bias[n0];
    #pragma unroll
    for (int i = 0; i < 4; ++i) {
      #pragma unroll
      for (int r = 0; r < 4; ++r) {
        const int m0 = (brow << 7) + wr + i * 16 + fq * 4 + r;
        const float v = acc[i][j][r] + bv;
        if (EPI == 0) {
          const int sect = n0 >> 10, cc = n0 & 1023;
          const int h = cc >> 6, d = cc & 63;
          const int b = m0 >> 11, t = m0 & 2047;
          const size_t idx = ((size_t)((b << 4) + h) * 2048 + t) * 64 + d;
          // Q pre-scaled by 1/sqrt(D) * log2(e) so flash uses exp2 directly
          if (sect == 0)      oQ[idx] = bfr(v * 0.1803368801f);
          else if (sect == 1) oK[idx] = bfr(v);
          else                oV[idx] = bfr(v);
        } else {
          oF[(size_t)m0 * N + n0] = v;
        }
      }
    }
  }
}

// ---------------- flash attention, swapped-QK^T 32x32, paired + dbuf ----------------
// grid = 512: bid = p*64 + bh (bh fastest -> all blocks of a bh on XCD bh%8).
// Block processes q-tiles g=p and g=15-p sequentially: constant 34 kv-iters/block.
// Staging double-buffered with counted vmcnt (T3/T4): loads for tile kt+1 stay in
// flight across the barrier while tile kt computes.
__global__ __launch_bounds__(256, 2) void flash_kernel(
    const u16b* __restrict__ Q, const u16b* __restrict__ K,
    const u16b* __restrict__ Vt, u16b* __restrict__ O) {
  __shared__ u16b smem[16384];  // 2 buffers x (K 8KB + V 8KB) = 32 KB
  const int bid = blockIdx.x;
  const int bh = bid & 63;
  const int p = bid >> 6;  // 0..7
  const int tid = threadIdx.x, wid = tid >> 6, lane = tid & 63;
  const int ln31 = lane & 31, hi = lane >> 5;
  const size_t baseQK = (size_t)bh * 2048 * 64;
  const size_t baseV = (size_t)bh * 64 * 2048;
  const int srow = wid * 8 + (lane >> 3);
  const int sc = ((lane & 7) ^ (srow & 7)) << 3;  // pre-swizzled source chunk
  const int b = bh >> 4, h = bh & 15;

  #pragma unroll 1
  for (int pass = 0; pass < 2; ++pass) {
    const int g = pass ? (15 - p) : p;
    const int q0 = g << 7;
    const int q0w = q0 + wid * 32;
    const int NT = 2 * g + 2;   // kv tiles this pass
    const int LT = q0w >> 6;    // last kv tile this wave computes

    // Q fragments (B-operand): qf[kk] = Q[q0w+ln31][16*kk + 8*hi .. +8]
    bf16x8 qf[4];
    {
      const u16b* qp = Q + baseQK + (size_t)(q0w + ln31) * 64 + hi * 8;
      #pragma unroll
      for (int kk = 0; kk < 4; ++kk) qf[kk] = *(const bf16x8*)(qp + kk * 16);
    }

    float m_run = -3e38f, l_run = 0.f;
    f32x16 oa0 = {}, oa1 = {};

    // ---- prologue: stage tiles 0 and 1 (4 GLDS each per wave) ----
    {
      char* kb = (char*)smem;
      GLDS(K + baseQK + (size_t)(srow) * 64 + sc,             kb + wid * 1024);
      GLDS(K + baseQK + (size_t)(32 + srow) * 64 + sc,        kb + 4096 + wid * 1024);
      GLDS(Vt + baseV + (size_t)srow * 2048 + sc,             kb + 8192 + wid * 1024);
      GLDS(Vt + baseV + (size_t)(32 + srow) * 2048 + sc,      kb + 12288 + wid * 1024);
      char* kb1 = (char*)smem + 16384;
      GLDS(K + baseQK + (size_t)(64 + srow) * 64 + sc,        kb1 + wid * 1024);
      GLDS(K + baseQK + (size_t)(96 + srow) * 64 + sc,        kb1 + 4096 + wid * 1024);
      GLDS(Vt + baseV + (size_t)srow * 2048 + 64 + sc,        kb1 + 8192 + wid * 1024);
      GLDS(Vt + baseV + (size_t)(32 + srow) * 2048 + 64 + sc, kb1 + 12288 + wid * 1024);
    }

    #pragma unroll 1
    for (int kt = 0; kt < NT; ++kt) {
      // own oldest 4 loads (tile kt) done; tile kt+1's 4 stay in flight
      if (kt + 1 < NT) asm volatile("s_waitcnt vmcnt(4)" ::: "memory");
      else             asm volatile("s_waitcnt vmcnt(0)" ::: "memory");
      __builtin_amdgcn_s_barrier();

      if (kt <= LT) {
        const int k0 = kt << 6;
        const char* kb = (const char*)smem + (kt & 1) * 16384;
        const char* vb = kb + 8192;
        const bool dodiag = (kt == LT);
        const bool do1 = (k0 + 32 <= q0w + 31);

        // ---- QK^T (swapped): S^T[kv][q=ln31], log2-domain ----
        f32x16 s0 = {}, s1 = {};
        __builtin_amdgcn_s_setprio(1);
        #pragma unroll
        for (int kk = 0; kk < 4; ++kk) {
          const int ch = ((2 * kk + hi) ^ (ln31 & 7));
          const bf16x8 kf = *(const bf16x8*)(kb + ln31 * 128 + ch * 16);
          s0 = __builtin_amdgcn_mfma_f32_32x32x16_bf16(kf, qf[kk], s0, 0, 0, 0);
        }
        if (do1) {
          #pragma unroll
          for (int kk = 0; kk < 4; ++kk) {
            const int row = 32 + ln31;
            const int ch = ((2 * kk + hi) ^ (row & 7));
            const bf16x8 kf = *(const bf16x8*)(kb + row * 128 + ch * 16);
            s1 = __builtin_amdgcn_mfma_f32_32x32x16_bf16(kf, qf[kk], s1, 0, 0, 0);
          }
        }
        __builtin_amdgcn_s_setprio(0);

        if (dodiag) {  // causal mask
          const int q = q0w + ln31;
          #pragma unroll
          for (int r = 0; r < 16; ++r) {
            const int kvr = k0 + (r & 3) + 8 * (r >> 2) + 4 * hi;
            if (kvr > q) s0[r] = -3e38f;
            if (kvr + 32 > q) s1[r] = -3e38f;
          }
        }

        // ---- online softmax, lane-local ----
        float tm = s0[0];
        #pragma unroll
        for (int r = 1; r < 16; ++r) tm = fmaxf(tm, s0[r]);
        if (do1) {
          #pragma unroll
          for (int r = 0; r < 16; ++r) tm = fmaxf(tm, s1[r]);
        }
        tm = fmaxf(tm, __shfl_xor(tm, 32));
        const float mnew = fmaxf(m_run, tm);
        const float scale = __builtin_amdgcn_exp2f(m_run - mnew);
        m_run = mnew;
        float rs = 0.f;
        #pragma unroll
        for (int r = 0; r < 16; ++r) { s0[r] = __builtin_amdgcn_exp2f(s0[r] - mnew); rs += s0[r]; }
        if (do1) {
          #pragma unroll
          for (int r = 0; r < 16; ++r) { s1[r] = __builtin_amdgcn_exp2f(s1[r] - mnew); rs += s1[r]; }
        }
        rs += __shfl_xor(rs, 32);
        l_run = l_run * scale + rs;
        #pragma unroll
        for (int r = 0; r < 16; ++r) { oa0[r] *= scale; oa1[r] *= scale; }

        // ---- P -> bf16 B-fragments via pk2 + permlane32_swap (T12) ----
        unsigned w[16];
#define MKPA(W0, W1, W2, W3, P0, P1, P2, P3, P4, P5, P6, P7)                 \
        {                                                                     \
          unsigned a0 = pk2(P0, P1), a1 = pk2(P2, P3);                        \
          unsigned b0 = pk2(P4, P5), b1 = pk2(P6, P7);                        \
          auto r0 = __builtin_amdgcn_permlane32_swap(a0, b0, false, false);   \
          auto r1 = __builtin_amdgcn_permlane32_swap(a1, b1, false, false);   \
          unsigned o0[2], o1[2];                                              \
          __builtin_memcpy(o0, &r0, 8); __builtin_memcpy(o1, &r1, 8);         \
          W0 = o0[0]; W2 = o0[1]; W1 = o1[0]; W3 = o1[1];                     \
        }
        MKPA(w[0], w[1], w[2], w[3],    s0[0], s0[1], s0[2], s0[3], s0[4], s0[5], s0[6], s0[7]);
        MKPA(w[4], w[5], w[6], w[7],    s0[8], s0[9], s0[10], s0[11], s0[12], s0[13], s0[14], s0[15]);
        if (do1) {
          MKPA(w[8], w[9], w[10], w[11],   s1[0], s1[1], s1[2], s1[3], s1[4], s1[5], s1[6], s1[7]);
          MKPA(w[12], w[13], w[14], w[15], s1[8], s1[9], s1[10], s1[11], s1[12], s1[13], s1[14], s1[15]);
        }
#undef MKPA

        // ---- PV (swapped): oa[t] += mfma(V^T frag, P frag) ----
        union WB { unsigned u[4]; bf16x8 v; };
        __builtin_amdgcn_s_setprio(1);
        #pragma unroll
        for (int sl = 0; sl < 2; ++sl) {
          WB pb; pb.u[0] = w[sl * 4]; pb.u[1] = w[sl * 4 + 1];
          pb.u[2] = w[sl * 4 + 2]; pb.u[3] = w[sl * 4 + 3];
          const int ch0 = ((2 * sl + hi) ^ (ln31 & 7));
          const bf16x8 vf0 = *(const bf16x8*)(vb + ln31 * 128 + ch0 * 16);
          oa0 = __builtin_amdgcn_mfma_f32_32x32x16_bf16(vf0, pb.v, oa0, 0, 0, 0);
          const int row1 = 32 + ln31;
          const int ch1 = ((2 * sl + hi) ^ (row1 & 7));
          const bf16x8 vf1 = *(const bf16x8*)(vb + row1 * 128 + ch1 * 16);
          oa1 = __builtin_amdgcn_mfma_f32_32x32x16_bf16(vf1, pb.v, oa1, 0, 0, 0);
        }
        if (do1) {
          #pragma unroll
          for (int sl = 2; sl < 4; ++sl) {
            WB pb; pb.u[0] = w[sl * 4]; pb.u[1] = w[sl * 4 + 1];
            pb.u[2] = w[sl * 4 + 2]; pb.u[3] = w[sl * 4 + 3];
            const int ch0 = ((2 * sl + hi) ^ (ln31 & 7));
            const bf16x8 vf0 = *(const bf16x8*)(vb + ln31 * 128 + ch0 * 16);
            oa0 = __builtin_amdgcn_mfma_f32_32x32x16_bf16(vf0, pb.v, oa0, 0, 0, 0);
            const int row1 = 32 + ln31;
            const int ch1 = ((2 * sl + hi) ^ (row1 & 7));
            const bf16x8 vf1 = *(const bf16x8*)(vb + row1 * 128 + ch1 * 16);
            oa1 = __builtin_amdgcn_mfma_f32_32x32x16_bf16(vf1, pb.v, oa1, 0, 0, 0);
          }
        }
        __builtin_amdgcn_s_setprio(0);
      }

      __builtin_amdgcn_s_barrier();  // all waves done reading buf[kt&1]

      if (kt + 2 < NT) {  // re-stage buf[kt&1] with tile kt+2
        const int k0 = (kt + 2) << 6;
        char* kb = (char*)smem + (kt & 1) * 16384;
        GLDS(K + baseQK + (size_t)(k0 + srow) * 64 + sc,        kb + wid * 1024);
        GLDS(K + baseQK + (size_t)(k0 + 32 + srow) * 64 + sc,   kb + 4096 + wid * 1024);
        GLDS(Vt + baseV + (size_t)srow * 2048 + k0 + sc,        kb + 8192 + wid * 1024);
        GLDS(Vt + baseV + (size_t)(32 + srow) * 2048 + k0 + sc, kb + 12288 + wid * 1024);
      }
    }

    // ---- epilogue: lane owns output row q = q0w+ln31 ----
    const float inv = 1.0f / l_run;
    const int q = q0w + ln31;
    u16b* orow = O + (size_t)(b * 2048 + q) * 1024 + h * 64;
    #pragma unroll
    for (int rq = 0; rq < 4; ++rq) {
      u16x4 v0, v1;
      #pragma unroll
      for (int j = 0; j < 4; ++j) {
        v0[j] = bfr(oa0[4 * rq + j] * inv);
        v1[j] = bfr(oa1[4 * rq + j] * inv);
      }
      const int d0 = 8 * rq + 4 * hi;
      *(u16x4*)(orow + d0) = v0;
      *(u16x4*)(orow + 32 + d0) = v1;
    }
    __builtin_amdgcn_s_barrier();  // don't let pass+1 staging race pass-0 LDS reads
  }
}

extern "C" void kernel_launch(void* const* d_in, const int* in_sizes, int n_in,
                              void* d_out, int out_size, void* d_ws, size_t ws_size,
                              hipStream_t stream) {
  const float* x      = (const float*)d_in[0];
  const float* w_attn = (const float*)d_in[1];
  const float* b_attn = (const float*)d_in[2];
  const float* w_proj = (const float*)d_in[3];
  const float* b_proj = (const float*)d_in[4];
  float* out = (float*)d_out;
  char* ws = (char*)d_ws;

  u16b* xb  = (u16b*)(ws + 0);          // [8192][1024] bf16 x; later reused as attn_out
  u16b* waT = (u16b*)(ws + 16777216);   // [3072][1024] w_attn^T bf16
  u16b* wpT = (u16b*)(ws + 23068672);   // [1024][1024] w_proj^T bf16
  u16b* Qb  = (u16b*)(ws + 25165824);   // [64 bh][2048][64]
  u16b* Kb  = (u16b*)(ws + 41943040);
  u16b* Vb  = (u16b*)(ws + 58720256);
  u16b* Vtb = (u16b*)(ws + 75497472);   // [64 bh][64][2048]
  u16b* attn = xb;

  cvt_bf16_kernel<<<2048, 256, 0, stream>>>(x, xb, (8192 * 1024) / 4);
  transpose_cvt_kernel<<<16 * 48, 256, 0, stream>>>(w_attn, waT, 1024, 3072);
  transpose_cvt_kernel<<<16 * 16, 256, 0, stream>>>(w_proj, wpT, 1024, 1024);
  gemm128_kernel<0><<<64 * 24, 256, 0, stream>>>(xb, waT, b_attn, Qb, Kb, Vb, nullptr,
                                                 8192, 3072, 1024);
  transpose_v_kernel<<<64 * 32, 256, 0, stream>>>(Vb, Vtb);
  flash_kernel<<<512, 256, 0, stream>>>(Qb, Kb, Vtb, attn);
  gemm128_kernel<1><<<64 * 8, 256, 0, stream>>>(attn, wpT, b_proj, nullptr, nullptr, nullptr,
                                                out, 8192, 1024, 1024);
}

// Round 4
// 181.687 us; speedup vs baseline: 1.2841x; 1.0850x over previous
//
#include <hip/hip_runtime.h>

// CausalSelfAttention: B=4, T=2048, C=1024, H=16, D=64
// Pipeline: cvt(x,w) -> qkv GEMM (dbuf, XCD-chunked, LDS-staged coalesced scatter)
//           -> V transpose -> flash attn (swapped 32x32, paired, dbuf) -> proj GEMM

typedef unsigned short u16b;
typedef __bf16 bf16x8 __attribute__((ext_vector_type(8)));
typedef float f32x4 __attribute__((ext_vector_type(4)));
typedef float f32x16 __attribute__((ext_vector_type(16)));
typedef unsigned short u16x4 __attribute__((ext_vector_type(4)));

#define AS1(p) ((const __attribute__((address_space(1))) void*)(p))
#define AS3(p) ((__attribute__((address_space(3))) void*)(p))
#define GLDS(g, l) __builtin_amdgcn_global_load_lds(AS1(g), AS3(l), 16, 0, 0)

__device__ __forceinline__ u16b bfr(float v) {  // f32 -> bf16 bits, RNE
  union { float f; unsigned u; } x; x.f = v;
  unsigned r = x.u + 0x7fffu + ((x.u >> 16) & 1u);
  return (u16b)(r >> 16);
}

__device__ __forceinline__ unsigned pk2(float lo, float hi) {  // pack 2 f32 -> 2 bf16 in u32
  union { __bf16 h[2]; unsigned u; } t;
  t.h[0] = (__bf16)lo; t.h[1] = (__bf16)hi;
  return t.u;
}

// ---------------- x (fp32) -> bf16, vectorized ----------------
__global__ __launch_bounds__(256) void cvt_bf16_kernel(
    const float* __restrict__ src, u16b* __restrict__ dst, int n4) {
  int i = blockIdx.x * 256 + threadIdx.x;
  const int stride = gridDim.x * 256;
  for (; i < n4; i += stride) {
    const float4 v = reinterpret_cast<const float4*>(src)[i];
    u16x4 o;
    o[0] = bfr(v.x); o[1] = bfr(v.y); o[2] = bfr(v.z); o[3] = bfr(v.w);
    reinterpret_cast<u16x4*>(dst)[i] = o;
  }
}

// ---------------- weights: src[R][C] fp32 -> dst[C][R] bf16 (transpose) ----------------
__global__ __launch_bounds__(256) void transpose_cvt_kernel(
    const float* __restrict__ src, u16b* __restrict__ dst, int R, int C) {
  __shared__ u16b tile[64][72];
  const int nc = C >> 6;
  const int br = blockIdx.x / nc, bc = blockIdx.x % nc;
  const int r0 = br << 6, c0 = bc << 6;
  const int c = threadIdx.x & 63, r4 = threadIdx.x >> 6;
  #pragma unroll
  for (int i = 0; i < 16; ++i) {
    const int r = r4 + 4 * i;
    tile[r][c] = bfr(src[(size_t)(r0 + r) * C + c0 + c]);
  }
  __syncthreads();
  #pragma unroll
  for (int i = 0; i < 16; ++i) {
    const int rr = r4 + 4 * i;
    dst[(size_t)(c0 + rr) * R + r0 + c] = tile[c][rr];
  }
}

// ---------------- V [bh][2048][64] -> Vt [bh][64][2048] (bf16) ----------------
__global__ __launch_bounds__(256) void transpose_v_kernel(
    const u16b* __restrict__ V, u16b* __restrict__ Vt) {
  __shared__ u16b tile[64][72];
  const int bid = blockIdx.x;
  const int bh = bid >> 5, t0 = (bid & 31) << 6;
  const int c = threadIdx.x & 63, r4 = threadIdx.x >> 6;
  const u16b* src = V + ((size_t)bh * 2048 + t0) * 64;
  #pragma unroll
  for (int i = 0; i < 16; ++i) {
    const int t = r4 + 4 * i;
    tile[t][c] = src[(size_t)t * 64 + c];
  }
  __syncthreads();
  u16b* dst = Vt + (size_t)bh * 64 * 2048 + t0;
  #pragma unroll
  for (int i = 0; i < 16; ++i) {
    const int d = r4 + 4 * i;
    dst[(size_t)d * 2048 + c] = tile[c][d];
  }
}

// ---------------- 128x128 tile bf16 GEMM: dbuf counted-vmcnt + XCD chunking ----------------
// C[M][N] = A[M][K] * Bt[N][K]^T + bias
// EPI==0: scatter Q(scaled)/K/V as [B,H,T,D] bf16 via LDS-staged coalesced epilogue
// EPI==1: fp32 out [M][N]
template <int EPI>
__global__ __launch_bounds__(256, 2) void gemm128_kernel(
    const u16b* __restrict__ A, const u16b* __restrict__ Bt,
    const float* __restrict__ bias,
    u16b* __restrict__ oQ, u16b* __restrict__ oK, u16b* __restrict__ oV,
    float* __restrict__ oF, int M, int N, int K) {
  __shared__ u16b smem[16384];  // 2 buf x (As 8KB + Bs 8KB); epilogue reuses all 32KB
  const int tid = threadIdx.x;
  const int wid = tid >> 6, lane = tid & 63;
  const int nb = N >> 7;
  // XCD-chunked bijection (gridDim.x % 8 == 0): all blocks sharing an A-panel on one XCD
  const int lin = (blockIdx.x & 7) * ((int)gridDim.x >> 3) + (blockIdx.x >> 3);
  const int brow = lin / nb, bcol = lin % nb;
  const int wr = (wid >> 1) << 6, wc = (wid & 1) << 6;

  f32x4 acc[4][4] = {};

  const int ar = (wid << 4) + (lane >> 2);
  const int ac = (lane & 3) << 3;
  const u16b* Ab = A + (size_t)((brow << 7) + ar) * K + ac;
  const u16b* Bb = Bt + (size_t)((bcol << 7) + ar) * K + ac;
  const int fr = lane & 15;
  const int fk = (lane >> 4) << 3;
  const int nk = K >> 5;

#define STAGE(bufi, kk)                                                        \
  {                                                                            \
    char* sb = (char*)smem + (bufi) * 16384;                                   \
    GLDS(Ab + (kk),                  sb + wid * 1024);                         \
    GLDS(Ab + (size_t)64 * K + (kk), sb + 4096 + wid * 1024);                  \
    GLDS(Bb + (kk),                  sb + 8192 + wid * 1024);                  \
    GLDS(Bb + (size_t)64 * K + (kk), sb + 12288 + wid * 1024);                 \
  }

  STAGE(0, 0);
  STAGE(1, 32);

  #pragma unroll 1
  for (int kt = 0; kt < nk; ++kt) {
    if (kt + 1 < nk) asm volatile("s_waitcnt vmcnt(4)" ::: "memory");
    else             asm volatile("s_waitcnt vmcnt(0)" ::: "memory");
    __builtin_amdgcn_s_barrier();

    const u16b* As = (const u16b*)((const char*)smem + (kt & 1) * 16384);
    const u16b* Bs = As + 4096;
    bf16x8 af[4], bfv[4];
    #pragma unroll
    for (int i = 0; i < 4; ++i)
      af[i] = *(const bf16x8*)&As[(wr + i * 16 + fr) * 32 + fk];
    #pragma unroll
    for (int j = 0; j < 4; ++j)
      bfv[j] = *(const bf16x8*)&Bs[(wc + j * 16 + fr) * 32 + fk];
    __builtin_amdgcn_s_setprio(1);
    #pragma unroll
    for (int i = 0; i < 4; ++i)
      #pragma unroll
      for (int j = 0; j < 4; ++j)
        acc[i][j] = __builtin_amdgcn_mfma_f32_16x16x32_bf16(af[i], bfv[j], acc[i][j], 0, 0, 0);
    __builtin_amdgcn_s_setprio(0);

    __builtin_amdgcn_s_barrier();
    if (kt + 2 < nk) STAGE(kt & 1, (kt + 2) << 5);
  }
#undef STAGE

  const int fq = lane >> 4;
  if (EPI == 1) {
    #pragma unroll
    for (int j = 0; j < 4; ++j) {
      const int n0 = (bcol << 7) + wc + j * 16 + fr;
      const float bv = bias[n0];
      #pragma unroll
      for (int i = 0; i < 4; ++i) {
        #pragma unroll
        for (int r = 0; r < 4; ++r) {
          const int m0 = (brow << 7) + wr + i * 16 + fq * 4 + r;
          oF[(size_t)m0 * N + n0] = acc[i][j][r] + bv;
        }
      }
    }
  } else {
    // sect uniform per block (128 | 1024)
    const int sect = (bcol << 7) >> 10;
    const float qs = (sect == 0) ? 0.1803368801f : 1.0f;  // 1/sqrt(64)*log2(e) folded into Q
    u16b* oPtr = (sect == 0) ? oQ : ((sect == 1) ? oK : oV);
    u16b* tile = (u16b*)smem;  // logical [m 128][n 128] bf16, chunk-swizzled
    // acc -> LDS (swizzle: 16B-chunk index ^= m&7)
    #pragma unroll
    for (int j = 0; j < 4; ++j) {
      const int n = wc + j * 16 + fr;
      const float bv = bias[(bcol << 7) + n];
      #pragma unroll
      for (int i = 0; i < 4; ++i) {
        #pragma unroll
        for (int r = 0; r < 4; ++r) {
          const int m = wr + i * 16 + fq * 4 + r;
          const int byteoff = m * 256 + (((n >> 3) ^ (m & 7)) << 4) + ((n & 7) << 1);
          *(u16b*)((char*)tile + byteoff) = bfr((acc[i][j][r] + bv) * qs);
        }
      }
    }
    __syncthreads();
    // LDS -> global: 8 lanes cover one (t,h) 128B row; instruction = contiguous 1KB
    const int nh = wid >> 1;
    const int c = lane & 7;
    #pragma unroll
    for (int it = 0; it < 8; ++it) {
      const int m = ((wid & 1) << 6) + (it << 3) + (lane >> 3);
      const int chunk = (nh << 3) + (c ^ (m & 7));
      const bf16x8 val = *(const bf16x8*)((const char*)tile + m * 256 + chunk * 16);
      const int m0 = (brow << 7) + m;
      const int n0 = (bcol << 7) + (nh << 6) + (c << 3);
      const int bb = m0 >> 11, tt = m0 & 2047;
      const int h = (n0 >> 6) & 15, d = n0 & 63;
      *(bf16x8*)(oPtr + (((size_t)(bb * 16 + h) * 2048 + tt) * 64 + d)) = val;
    }
  }
}

// ---------------- flash attention, swapped-QK^T 32x32, paired + dbuf ----------------
__global__ __launch_bounds__(256, 2) void flash_kernel(
    const u16b* __restrict__ Q, const u16b* __restrict__ K,
    const u16b* __restrict__ Vt, u16b* __restrict__ O) {
  __shared__ u16b smem[16384];  // 2 buffers x (K 8KB + V 8KB) = 32 KB
  const int bid = blockIdx.x;
  const int bh = bid & 63;
  const int p = bid >> 6;  // 0..7
  const int tid = threadIdx.x, wid = tid >> 6, lane = tid & 63;
  const int ln31 = lane & 31, hi = lane >> 5;
  const size_t baseQK = (size_t)bh * 2048 * 64;
  const size_t baseV = (size_t)bh * 64 * 2048;
  const int srow = wid * 8 + (lane >> 3);
  const int sc = ((lane & 7) ^ (srow & 7)) << 3;  // pre-swizzled source chunk
  const int b = bh >> 4, h = bh & 15;

  #pragma unroll 1
  for (int pass = 0; pass < 2; ++pass) {
    const int g = pass ? (15 - p) : p;
    const int q0 = g << 7;
    const int q0w = q0 + wid * 32;
    const int NT = 2 * g + 2;   // kv tiles this pass
    const int LT = q0w >> 6;    // last kv tile this wave computes

    bf16x8 qf[4];
    {
      const u16b* qp = Q + baseQK + (size_t)(q0w + ln31) * 64 + hi * 8;
      #pragma unroll
      for (int kk = 0; kk < 4; ++kk) qf[kk] = *(const bf16x8*)(qp + kk * 16);
    }

    float m_run = -3e38f, l_run = 0.f;
    f32x16 oa0 = {}, oa1 = {};

    {
      char* kb = (char*)smem;
      GLDS(K + baseQK + (size_t)(srow) * 64 + sc,             kb + wid * 1024);
      GLDS(K + baseQK + (size_t)(32 + srow) * 64 + sc,        kb + 4096 + wid * 1024);
      GLDS(Vt + baseV + (size_t)srow * 2048 + sc,             kb + 8192 + wid * 1024);
      GLDS(Vt + baseV + (size_t)(32 + srow) * 2048 + sc,      kb + 12288 + wid * 1024);
      char* kb1 = (char*)smem + 16384;
      GLDS(K + baseQK + (size_t)(64 + srow) * 64 + sc,        kb1 + wid * 1024);
      GLDS(K + baseQK + (size_t)(96 + srow) * 64 + sc,        kb1 + 4096 + wid * 1024);
      GLDS(Vt + baseV + (size_t)srow * 2048 + 64 + sc,        kb1 + 8192 + wid * 1024);
      GLDS(Vt + baseV + (size_t)(32 + srow) * 2048 + 64 + sc, kb1 + 12288 + wid * 1024);
    }

    #pragma unroll 1
    for (int kt = 0; kt < NT; ++kt) {
      if (kt + 1 < NT) asm volatile("s_waitcnt vmcnt(4)" ::: "memory");
      else             asm volatile("s_waitcnt vmcnt(0)" ::: "memory");
      __builtin_amdgcn_s_barrier();

      if (kt <= LT) {
        const int k0 = kt << 6;
        const char* kb = (const char*)smem + (kt & 1) * 16384;
        const char* vb = kb + 8192;
        const bool dodiag = (kt == LT);
        const bool do1 = (k0 + 32 <= q0w + 31);

        f32x16 s0 = {}, s1 = {};
        __builtin_amdgcn_s_setprio(1);
        #pragma unroll
        for (int kk = 0; kk < 4; ++kk) {
          const int ch = ((2 * kk + hi) ^ (ln31 & 7));
          const bf16x8 kf = *(const bf16x8*)(kb + ln31 * 128 + ch * 16);
          s0 = __builtin_amdgcn_mfma_f32_32x32x16_bf16(kf, qf[kk], s0, 0, 0, 0);
        }
        if (do1) {
          #pragma unroll
          for (int kk = 0; kk < 4; ++kk) {
            const int row = 32 + ln31;
            const int ch = ((2 * kk + hi) ^ (row & 7));
            const bf16x8 kf = *(const bf16x8*)(kb + row * 128 + ch * 16);
            s1 = __builtin_amdgcn_mfma_f32_32x32x16_bf16(kf, qf[kk], s1, 0, 0, 0);
          }
        }
        __builtin_amdgcn_s_setprio(0);

        if (dodiag) {
          const int q = q0w + ln31;
          #pragma unroll
          for (int r = 0; r < 16; ++r) {
            const int kvr = k0 + (r & 3) + 8 * (r >> 2) + 4 * hi;
            if (kvr > q) s0[r] = -3e38f;
            if (kvr + 32 > q) s1[r] = -3e38f;
          }
        }

        float tm = s0[0];
        #pragma unroll
        for (int r = 1; r < 16; ++r) tm = fmaxf(tm, s0[r]);
        if (do1) {
          #pragma unroll
          for (int r = 0; r < 16; ++r) tm = fmaxf(tm, s1[r]);
        }
        tm = fmaxf(tm, __shfl_xor(tm, 32));
        const float mnew = fmaxf(m_run, tm);
        const float scale = __builtin_amdgcn_exp2f(m_run - mnew);
        m_run = mnew;
        float rs = 0.f;
        #pragma unroll
        for (int r = 0; r < 16; ++r) { s0[r] = __builtin_amdgcn_exp2f(s0[r] - mnew); rs += s0[r]; }
        if (do1) {
          #pragma unroll
          for (int r = 0; r < 16; ++r) { s1[r] = __builtin_amdgcn_exp2f(s1[r] - mnew); rs += s1[r]; }
        }
        rs += __shfl_xor(rs, 32);
        l_run = l_run * scale + rs;
        #pragma unroll
        for (int r = 0; r < 16; ++r) { oa0[r] *= scale; oa1[r] *= scale; }

        unsigned w[16];
#define MKPA(W0, W1, W2, W3, P0, P1, P2, P3, P4, P5, P6, P7)                 \
        {                                                                     \
          unsigned a0 = pk2(P0, P1), a1 = pk2(P2, P3);                        \
          unsigned b0 = pk2(P4, P5), b1 = pk2(P6, P7);                        \
          auto r0 = __builtin_amdgcn_permlane32_swap(a0, b0, false, false);   \
          auto r1 = __builtin_amdgcn_permlane32_swap(a1, b1, false, false);   \
          unsigned o0[2], o1[2];                                              \
          __builtin_memcpy(o0, &r0, 8); __builtin_memcpy(o1, &r1, 8);         \
          W0 = o0[0]; W2 = o0[1]; W1 = o1[0]; W3 = o1[1];                     \
        }
        MKPA(w[0], w[1], w[2], w[3],    s0[0], s0[1], s0[2], s0[3], s0[4], s0[5], s0[6], s0[7]);
        MKPA(w[4], w[5], w[6], w[7],    s0[8], s0[9], s0[10], s0[11], s0[12], s0[13], s0[14], s0[15]);
        if (do1) {
          MKPA(w[8], w[9], w[10], w[11],   s1[0], s1[1], s1[2], s1[3], s1[4], s1[5], s1[6], s1[7]);
          MKPA(w[12], w[13], w[14], w[15], s1[8], s1[9], s1[10], s1[11], s1[12], s1[13], s1[14], s1[15]);
        }
#undef MKPA

        union WB { unsigned u[4]; bf16x8 v; };
        __builtin_amdgcn_s_setprio(1);
        #pragma unroll
        for (int sl = 0; sl < 2; ++sl) {
          WB pb; pb.u[0] = w[sl * 4]; pb.u[1] = w[sl * 4 + 1];
          pb.u[2] = w[sl * 4 + 2]; pb.u[3] = w[sl * 4 + 3];
          const int ch0 = ((2 * sl + hi) ^ (ln31 & 7));
          const bf16x8 vf0 = *(const bf16x8*)(vb + ln31 * 128 + ch0 * 16);
          oa0 = __builtin_amdgcn_mfma_f32_32x32x16_bf16(vf0, pb.v, oa0, 0, 0, 0);
          const int row1 = 32 + ln31;
          const int ch1 = ((2 * sl + hi) ^ (row1 & 7));
          const bf16x8 vf1 = *(const bf16x8*)(vb + row1 * 128 + ch1 * 16);
          oa1 = __builtin_amdgcn_mfma_f32_32x32x16_bf16(vf1, pb.v, oa1, 0, 0, 0);
        }
        if (do1) {
          #pragma unroll
          for (int sl = 2; sl < 4; ++sl) {
            WB pb; pb.u[0] = w[sl * 4]; pb.u[1] = w[sl * 4 + 1];
            pb.u[2] = w[sl * 4 + 2]; pb.u[3] = w[sl * 4 + 3];
            const int ch0 = ((2 * sl + hi) ^ (ln31 & 7));
            const bf16x8 vf0 = *(const bf16x8*)(vb + ln31 * 128 + ch0 * 16);
            oa0 = __builtin_amdgcn_mfma_f32_32x32x16_bf16(vf0, pb.v, oa0, 0, 0, 0);
            const int row1 = 32 + ln31;
            const int ch1 = ((2 * sl + hi) ^ (row1 & 7));
            const bf16x8 vf1 = *(const bf16x8*)(vb + row1 * 128 + ch1 * 16);
            oa1 = __builtin_amdgcn_mfma_f32_32x32x16_bf16(vf1, pb.v, oa1, 0, 0, 0);
          }
        }
        __builtin_amdgcn_s_setprio(0);
      }

      __builtin_amdgcn_s_barrier();

      if (kt + 2 < NT) {
        const int k0 = (kt + 2) << 6;
        char* kb = (char*)smem + (kt & 1) * 16384;
        GLDS(K + baseQK + (size_t)(k0 + srow) * 64 + sc,        kb + wid * 1024);
        GLDS(K + baseQK + (size_t)(k0 + 32 + srow) * 64 + sc,   kb + 4096 + wid * 1024);
        GLDS(Vt + baseV + (size_t)srow * 2048 + k0 + sc,        kb + 8192 + wid * 1024);
        GLDS(Vt + baseV + (size_t)(32 + srow) * 2048 + k0 + sc, kb + 12288 + wid * 1024);
      }
    }

    const float inv = 1.0f / l_run;
    const int q = q0w + ln31;
    u16b* orow = O + (size_t)(b * 2048 + q) * 1024 + h * 64;
    #pragma unroll
    for (int rq = 0; rq < 4; ++rq) {
      u16x4 v0, v1;
      #pragma unroll
      for (int j = 0; j < 4; ++j) {
        v0[j] = bfr(oa0[4 * rq + j] * inv);
        v1[j] = bfr(oa1[4 * rq + j] * inv);
      }
      const int d0 = 8 * rq + 4 * hi;
      *(u16x4*)(orow + d0) = v0;
      *(u16x4*)(orow + 32 + d0) = v1;
    }
    __builtin_amdgcn_s_barrier();
  }
}

extern "C" void kernel_launch(void* const* d_in, const int* in_sizes, int n_in,
                              void* d_out, int out_size, void* d_ws, size_t ws_size,
                              hipStream_t stream) {
  const float* x      = (const float*)d_in[0];
  const float* w_attn = (const float*)d_in[1];
  const float* b_attn = (const float*)d_in[2];
  const float* w_proj = (const float*)d_in[3];
  const float* b_proj = (const float*)d_in[4];
  float* out = (float*)d_out;
  char* ws = (char*)d_ws;

  u16b* xb  = (u16b*)(ws + 0);          // [8192][1024] bf16 x; later reused as attn_out
  u16b* waT = (u16b*)(ws + 16777216);   // [3072][1024] w_attn^T bf16
  u16b* wpT = (u16b*)(ws + 23068672);   // [1024][1024] w_proj^T bf16
  u16b* Qb  = (u16b*)(ws + 25165824);   // [64 bh][2048][64]
  u16b* Kb  = (u16b*)(ws + 41943040);
  u16b* Vb  = (u16b*)(ws + 58720256);
  u16b* Vtb = (u16b*)(ws + 75497472);   // [64 bh][64][2048]
  u16b* attn = xb;

  cvt_bf16_kernel<<<2048, 256, 0, stream>>>(x, xb, (8192 * 1024) / 4);
  transpose_cvt_kernel<<<16 * 48, 256, 0, stream>>>(w_attn, waT, 1024, 3072);
  transpose_cvt_kernel<<<16 * 16, 256, 0, stream>>>(w_proj, wpT, 1024, 1024);
  gemm128_kernel<0><<<64 * 24, 256, 0, stream>>>(xb, waT, b_attn, Qb, Kb, Vb, nullptr,
                                                 8192, 3072, 1024);
  transpose_v_kernel<<<64 * 32, 256, 0, stream>>>(Vb, Vtb);
  flash_kernel<<<512, 256, 0, stream>>>(Qb, Kb, Vtb, attn);
  gemm128_kernel<1><<<64 * 8, 256, 0, stream>>>(attn, wpT, b_proj, nullptr, nullptr, nullptr,
                                                out, 8192, 1024, 1024);
}

// Round 5
// 180.246 us; speedup vs baseline: 1.2943x; 1.0080x over previous
//
#include <hip/hip_runtime.h>

// CausalSelfAttention: B=4, T=2048, C=1024, H=16, D=64
// Pipeline: cvt(x,w) -> qkv GEMM (dbuf, XCD-chunked, LDS-staged coalesced scatter)
//           -> V transpose -> flash attn (swapped 32x32, KVBLK=128, defer-max, paired, dbuf)
//           -> proj GEMM

typedef unsigned short u16b;
typedef __bf16 bf16x8 __attribute__((ext_vector_type(8)));
typedef float f32x4 __attribute__((ext_vector_type(4)));
typedef float f32x16 __attribute__((ext_vector_type(16)));
typedef unsigned short u16x4 __attribute__((ext_vector_type(4)));

#define AS1(p) ((const __attribute__((address_space(1))) void*)(p))
#define AS3(p) ((__attribute__((address_space(3))) void*)(p))
#define GLDS(g, l) __builtin_amdgcn_global_load_lds(AS1(g), AS3(l), 16, 0, 0)

__device__ __forceinline__ u16b bfr(float v) {  // f32 -> bf16 bits, RNE
  union { float f; unsigned u; } x; x.f = v;
  unsigned r = x.u + 0x7fffu + ((x.u >> 16) & 1u);
  return (u16b)(r >> 16);
}

__device__ __forceinline__ unsigned pk2(float lo, float hi) {  // pack 2 f32 -> 2 bf16 in u32
  union { __bf16 h[2]; unsigned u; } t;
  t.h[0] = (__bf16)lo; t.h[1] = (__bf16)hi;
  return t.u;
}

__device__ __forceinline__ float max16(const f32x16& v) {
  float a0 = fmaxf(v[0], v[1]), a1 = fmaxf(v[2], v[3]);
  float a2 = fmaxf(v[4], v[5]), a3 = fmaxf(v[6], v[7]);
  float b0 = fmaxf(v[8], v[9]), b1 = fmaxf(v[10], v[11]);
  float b2 = fmaxf(v[12], v[13]), b3 = fmaxf(v[14], v[15]);
  float c0 = fmaxf(a0, a1), c1 = fmaxf(a2, a3);
  float c2 = fmaxf(b0, b1), c3 = fmaxf(b2, b3);
  return fmaxf(fmaxf(c0, c1), fmaxf(c2, c3));
}

__device__ __forceinline__ float sum16(const f32x16& v) {
  float a0 = v[0] + v[1], a1 = v[2] + v[3], a2 = v[4] + v[5], a3 = v[6] + v[7];
  float b0 = v[8] + v[9], b1 = v[10] + v[11], b2 = v[12] + v[13], b3 = v[14] + v[15];
  float c0 = a0 + a1, c1 = a2 + a3, c2 = b0 + b1, c3 = b2 + b3;
  return (c0 + c1) + (c2 + c3);
}

// ---------------- x (fp32) -> bf16, vectorized ----------------
__global__ __launch_bounds__(256) void cvt_bf16_kernel(
    const float* __restrict__ src, u16b* __restrict__ dst, int n4) {
  int i = blockIdx.x * 256 + threadIdx.x;
  const int stride = gridDim.x * 256;
  for (; i < n4; i += stride) {
    const float4 v = reinterpret_cast<const float4*>(src)[i];
    u16x4 o;
    o[0] = bfr(v.x); o[1] = bfr(v.y); o[2] = bfr(v.z); o[3] = bfr(v.w);
    reinterpret_cast<u16x4*>(dst)[i] = o;
  }
}

// ---------------- weights: src[R][C] fp32 -> dst[C][R] bf16 (transpose) ----------------
__global__ __launch_bounds__(256) void transpose_cvt_kernel(
    const float* __restrict__ src, u16b* __restrict__ dst, int R, int C) {
  __shared__ u16b tile[64][72];
  const int nc = C >> 6;
  const int br = blockIdx.x / nc, bc = blockIdx.x % nc;
  const int r0 = br << 6, c0 = bc << 6;
  const int c = threadIdx.x & 63, r4 = threadIdx.x >> 6;
  #pragma unroll
  for (int i = 0; i < 16; ++i) {
    const int r = r4 + 4 * i;
    tile[r][c] = bfr(src[(size_t)(r0 + r) * C + c0 + c]);
  }
  __syncthreads();
  #pragma unroll
  for (int i = 0; i < 16; ++i) {
    const int rr = r4 + 4 * i;
    dst[(size_t)(c0 + rr) * R + r0 + c] = tile[c][rr];
  }
}

// ---------------- V [bh][2048][64] -> Vt [bh][64][2048] (bf16) ----------------
__global__ __launch_bounds__(256) void transpose_v_kernel(
    const u16b* __restrict__ V, u16b* __restrict__ Vt) {
  __shared__ u16b tile[64][72];
  const int bid = blockIdx.x;
  const int bh = bid >> 5, t0 = (bid & 31) << 6;
  const int c = threadIdx.x & 63, r4 = threadIdx.x >> 6;
  const u16b* src = V + ((size_t)bh * 2048 + t0) * 64;
  #pragma unroll
  for (int i = 0; i < 16; ++i) {
    const int t = r4 + 4 * i;
    tile[t][c] = src[(size_t)t * 64 + c];
  }
  __syncthreads();
  u16b* dst = Vt + (size_t)bh * 64 * 2048 + t0;
  #pragma unroll
  for (int i = 0; i < 16; ++i) {
    const int d = r4 + 4 * i;
    dst[(size_t)d * 2048 + c] = tile[c][d];
  }
}

// ---------------- 128x128 tile bf16 GEMM: dbuf counted-vmcnt + XCD chunking ----------------
template <int EPI>
__global__ __launch_bounds__(256, 2) void gemm128_kernel(
    const u16b* __restrict__ A, const u16b* __restrict__ Bt,
    const float* __restrict__ bias,
    u16b* __restrict__ oQ, u16b* __restrict__ oK, u16b* __restrict__ oV,
    float* __restrict__ oF, int M, int N, int K) {
  __shared__ u16b smem[16384];  // 2 buf x (As 8KB + Bs 8KB); epilogue reuses all 32KB
  const int tid = threadIdx.x;
  const int wid = tid >> 6, lane = tid & 63;
  const int nb = N >> 7;
  const int lin = (blockIdx.x & 7) * ((int)gridDim.x >> 3) + (blockIdx.x >> 3);
  const int brow = lin / nb, bcol = lin % nb;
  const int wr = (wid >> 1) << 6, wc = (wid & 1) << 6;

  f32x4 acc[4][4] = {};

  const int ar = (wid << 4) + (lane >> 2);
  const int ac = (lane & 3) << 3;
  const u16b* Ab = A + (size_t)((brow << 7) + ar) * K + ac;
  const u16b* Bb = Bt + (size_t)((bcol << 7) + ar) * K + ac;
  const int fr = lane & 15;
  const int fk = (lane >> 4) << 3;
  const int nk = K >> 5;

#define STAGE(bufi, kk)                                                        \
  {                                                                            \
    char* sb = (char*)smem + (bufi) * 16384;                                   \
    GLDS(Ab + (kk),                  sb + wid * 1024);                         \
    GLDS(Ab + (size_t)64 * K + (kk), sb + 4096 + wid * 1024);                  \
    GLDS(Bb + (kk),                  sb + 8192 + wid * 1024);                  \
    GLDS(Bb + (size_t)64 * K + (kk), sb + 12288 + wid * 1024);                 \
  }

  STAGE(0, 0);
  STAGE(1, 32);

  #pragma unroll 1
  for (int kt = 0; kt < nk; ++kt) {
    if (kt + 1 < nk) asm volatile("s_waitcnt vmcnt(4)" ::: "memory");
    else             asm volatile("s_waitcnt vmcnt(0)" ::: "memory");
    __builtin_amdgcn_s_barrier();

    const u16b* As = (const u16b*)((const char*)smem + (kt & 1) * 16384);
    const u16b* Bs = As + 4096;
    bf16x8 af[4], bfv[4];
    #pragma unroll
    for (int i = 0; i < 4; ++i)
      af[i] = *(const bf16x8*)&As[(wr + i * 16 + fr) * 32 + fk];
    #pragma unroll
    for (int j = 0; j < 4; ++j)
      bfv[j] = *(const bf16x8*)&Bs[(wc + j * 16 + fr) * 32 + fk];
    __builtin_amdgcn_s_setprio(1);
    #pragma unroll
    for (int i = 0; i < 4; ++i)
      #pragma unroll
      for (int j = 0; j < 4; ++j)
        acc[i][j] = __builtin_amdgcn_mfma_f32_16x16x32_bf16(af[i], bfv[j], acc[i][j], 0, 0, 0);
    __builtin_amdgcn_s_setprio(0);

    __builtin_amdgcn_s_barrier();
    if (kt + 2 < nk) STAGE(kt & 1, (kt + 2) << 5);
  }
#undef STAGE

  const int fq = lane >> 4;
  if (EPI == 1) {
    #pragma unroll
    for (int j = 0; j < 4; ++j) {
      const int n0 = (bcol << 7) + wc + j * 16 + fr;
      const float bv = bias[n0];
      #pragma unroll
      for (int i = 0; i < 4; ++i) {
        #pragma unroll
        for (int r = 0; r < 4; ++r) {
          const int m0 = (brow << 7) + wr + i * 16 + fq * 4 + r;
          oF[(size_t)m0 * N + n0] = acc[i][j][r] + bv;
        }
      }
    }
  } else {
    const int sect = (bcol << 7) >> 10;
    const float qs = (sect == 0) ? 0.1803368801f : 1.0f;  // 1/sqrt(64)*log2(e) folded into Q
    u16b* oPtr = (sect == 0) ? oQ : ((sect == 1) ? oK : oV);
    u16b* tile = (u16b*)smem;  // logical [m 128][n 128] bf16, chunk-swizzled
    #pragma unroll
    for (int j = 0; j < 4; ++j) {
      const int n = wc + j * 16 + fr;
      const float bv = bias[(bcol << 7) + n];
      #pragma unroll
      for (int i = 0; i < 4; ++i) {
        #pragma unroll
        for (int r = 0; r < 4; ++r) {
          const int m = wr + i * 16 + fq * 4 + r;
          const int byteoff = m * 256 + (((n >> 3) ^ (m & 7)) << 4) + ((n & 7) << 1);
          *(u16b*)((char*)tile + byteoff) = bfr((acc[i][j][r] + bv) * qs);
        }
      }
    }
    __syncthreads();
    const int nh = wid >> 1;
    const int c = lane & 7;
    #pragma unroll
    for (int it = 0; it < 8; ++it) {
      const int m = ((wid & 1) << 6) + (it << 3) + (lane >> 3);
      const int chunk = (nh << 3) + (c ^ (m & 7));
      const bf16x8 val = *(const bf16x8*)((const char*)tile + m * 256 + chunk * 16);
      const int m0 = (brow << 7) + m;
      const int n0 = (bcol << 7) + (nh << 6) + (c << 3);
      const int bb = m0 >> 11, tt = m0 & 2047;
      const int h = (n0 >> 6) & 15, d = n0 & 63;
      *(bf16x8*)(oPtr + (((size_t)(bb * 16 + h) * 2048 + tt) * 64 + d)) = val;
    }
  }
}

// ---------------- flash attention: swapped 32x32, KVBLK=128, defer-max, paired, dbuf ----------------
// grid = 512: bid = p*64 + bh (bh fastest -> bh pinned to XCD bh%8).
// Block = 4 waves x 32 q-rows = 128 q. Passes g=p and g=15-p: 17 kv-tiles of 128 each.
// LDS per buffer: K [128 t][128B swz] 16KB + V [64 d][256B swz] 16KB; 2 buffers = 64KB.
__global__ __launch_bounds__(256, 2) void flash_kernel(
    const u16b* __restrict__ Q, const u16b* __restrict__ K,
    const u16b* __restrict__ Vt, u16b* __restrict__ O) {
  __shared__ u16b smem[32768];  // 64KB
  const int bid = blockIdx.x;
  const int bh = bid & 63;
  const int p = bid >> 6;  // 0..7
  const int tid = threadIdx.x, wid = tid >> 6, lane = tid & 63;
  const int ln31 = lane & 31, hi = lane >> 5;
  const int l7 = ln31 & 7;
  const size_t baseQK = (size_t)bh * 2048 * 64;
  const size_t baseV = (size_t)bh * 64 * 2048;
  const int b = bh >> 4, h = bh & 15;
  // K staging geometry: write i covers rows 8i..8i+7 (128B rows)
  const int rk = lane >> 3;                 // row offset within 8-row group
  const int sk = ((lane & 7) ^ rk) << 3;    // pre-swizzled source elem offset
  // V staging geometry: write i covers rows 4i..4i+3 (256B rows, 16 chunks)
  const int rv = lane >> 4;                 // row offset within 4-row group
  const int cv = lane & 15;                 // chunk

#define FSTAGE(kt, bi)                                                         \
  {                                                                            \
    char* kb_ = (char*)smem + (bi) * 32768 / 2 * 2;                            \
    kb_ = (char*)smem + (bi) * 32768;                                          \
    char* vb_ = kb_ + 16384;                                                   \
    const int k0_ = (kt) << 7;                                                 \
    _Pragma("unroll")                                                          \
    for (int c = 0; c < 4; ++c) {                                              \
      const int i = 4 * wid + c;                                               \
      const int r = 8 * i + rk;                                                \
      GLDS(K + baseQK + (size_t)(k0_ + r) * 64 + sk, kb_ + i * 1024);          \
    }                                                                          \
    _Pragma("unroll")                                                          \
    for (int c = 0; c < 4; ++c) {                                              \
      const int i = 4 * wid + c;                                               \
      const int r = 4 * i + rv;                                                \
      const int scv = (cv ^ (r & 7)) << 3;                                     \
      GLDS(Vt + baseV + (size_t)r * 2048 + k0_ + scv, vb_ + i * 1024);         \
    }                                                                          \
  }

  #pragma unroll 1
  for (int pass = 0; pass < 2; ++pass) {
    const int g = pass ? (15 - p) : p;
    const int NT = g + 1;
    const int q0w = (g << 7) + wid * 32;

    bf16x8 qf[4];
    {
      const u16b* qp = Q + baseQK + (size_t)(q0w + ln31) * 64 + hi * 8;
      #pragma unroll
      for (int kk = 0; kk < 4; ++kk) qf[kk] = *(const bf16x8*)(qp + kk * 16);
    }

    float m_run = -3e38f, l_run = 0.f;
    f32x16 oa0 = {}, oa1 = {};

    FSTAGE(0, 0);
    FSTAGE(1, 1);

    #pragma unroll 1
    for (int kt = 0; kt < NT; ++kt) {
      if (kt + 1 < NT) asm volatile("s_waitcnt vmcnt(8)" ::: "memory");
      else             asm volatile("s_waitcnt vmcnt(0)" ::: "memory");
      __builtin_amdgcn_s_barrier();

      const char* kb = (const char*)smem + (kt & 1) * 32768;
      const char* vb = kb + 16384;
      const bool diag = (kt == g);
      const int maxsub = diag ? wid : 3;  // wave-uniform

      // ---- QK^T (swapped): s[ss] = S^T[kv=32ss+crow][q=ln31], log2 domain ----
      f32x16 s[4] = {};
      __builtin_amdgcn_s_setprio(1);
      #pragma unroll
      for (int ss = 0; ss < 4; ++ss) {
        if (ss <= maxsub) {
          const int row = 32 * ss + ln31;
          #pragma unroll
          for (int kk = 0; kk < 4; ++kk) {
            const int ch = (2 * kk + hi) ^ l7;
            const bf16x8 kf = *(const bf16x8*)(kb + row * 128 + ch * 16);
            s[ss] = __builtin_amdgcn_mfma_f32_32x32x16_bf16(kf, qf[kk], s[ss], 0, 0, 0);
          }
        }
      }
      __builtin_amdgcn_s_setprio(0);

      // ---- causal mask: only subtile ss == wid of the diagonal tile is triangular ----
      if (diag) {
        #pragma unroll
        for (int ss = 0; ss < 4; ++ss) {
          if (ss == wid) {  // ss compile-time, predicate runtime (rule #20 safe)
            #pragma unroll
            for (int r = 0; r < 16; ++r) {
              const int kvr = (r & 3) + 8 * (r >> 2) + 4 * hi;
              if (kvr > ln31) s[ss][r] = -3e38f;
            }
          }
        }
      }

      // ---- online softmax, lane-local, defer-max (T13, THR=8) ----
      float tm = -3e38f;
      #pragma unroll
      for (int ss = 0; ss < 4; ++ss)
        if (ss <= maxsub) tm = fmaxf(tm, max16(s[ss]));
      tm = fmaxf(tm, __shfl_xor(tm, 32));

      if (!__all(tm <= m_run + 8.f)) {
        const float mnew = fmaxf(m_run, tm);
        const float scale = __builtin_amdgcn_exp2f(m_run - mnew);
        m_run = mnew;
        l_run *= scale;
        #pragma unroll
        for (int r = 0; r < 16; ++r) { oa0[r] *= scale; oa1[r] *= scale; }
      }

      float rs = 0.f;
      #pragma unroll
      for (int ss = 0; ss < 4; ++ss) {
        if (ss <= maxsub) {
          #pragma unroll
          for (int r = 0; r < 16; ++r)
            s[ss][r] = __builtin_amdgcn_exp2f(s[ss][r] - m_run);
          rs += sum16(s[ss]);
        }
      }
      rs += __shfl_xor(rs, 32);
      l_run += rs;

      // ---- pack (T12) + PV per subtile ----
      union WB { unsigned u[4]; bf16x8 v; };
      __builtin_amdgcn_s_setprio(1);
      #pragma unroll
      for (int ss = 0; ss < 4; ++ss) {
        if (ss <= maxsub) {
          WB pA, pB;
#define MKPA(W0, W1, W2, W3, P0, P1, P2, P3, P4, P5, P6, P7)                 \
          {                                                                   \
            unsigned a0 = pk2(P0, P1), a1 = pk2(P2, P3);                      \
            unsigned b0 = pk2(P4, P5), b1 = pk2(P6, P7);                      \
            auto r0 = __builtin_amdgcn_permlane32_swap(a0, b0, false, false); \
            auto r1 = __builtin_amdgcn_permlane32_swap(a1, b1, false, false); \
            unsigned o0[2], o1[2];                                            \
            __builtin_memcpy(o0, &r0, 8); __builtin_memcpy(o1, &r1, 8);       \
            W0 = o0[0]; W2 = o0[1]; W1 = o1[0]; W3 = o1[1];                   \
          }
          MKPA(pA.u[0], pA.u[1], pA.u[2], pA.u[3],
               s[ss][0], s[ss][1], s[ss][2], s[ss][3],
               s[ss][4], s[ss][5], s[ss][6], s[ss][7]);
          MKPA(pB.u[0], pB.u[1], pB.u[2], pB.u[3],
               s[ss][8], s[ss][9], s[ss][10], s[ss][11],
               s[ss][12], s[ss][13], s[ss][14], s[ss][15]);
#undef MKPA
          const int cxa = ((4 * ss + hi) ^ l7) << 4;      // slice 2ss
          const int cxb = ((4 * ss + 2 + hi) ^ l7) << 4;  // slice 2ss+1
          const char* v0 = vb + ln31 * 256;
          const char* v1 = vb + (32 + ln31) * 256;
          oa0 = __builtin_amdgcn_mfma_f32_32x32x16_bf16(*(const bf16x8*)(v0 + cxa), pA.v, oa0, 0, 0, 0);
          oa1 = __builtin_amdgcn_mfma_f32_32x32x16_bf16(*(const bf16x8*)(v1 + cxa), pA.v, oa1, 0, 0, 0);
          oa0 = __builtin_amdgcn_mfma_f32_32x32x16_bf16(*(const bf16x8*)(v0 + cxb), pB.v, oa0, 0, 0, 0);
          oa1 = __builtin_amdgcn_mfma_f32_32x32x16_bf16(*(const bf16x8*)(v1 + cxb), pB.v, oa1, 0, 0, 0);
        }
      }
      __builtin_amdgcn_s_setprio(0);

      __builtin_amdgcn_s_barrier();  // all waves done reading buf[kt&1]
      if (kt + 2 < NT) FSTAGE(kt + 2, kt & 1);
    }

    // ---- epilogue: lane owns output row q = q0w+ln31 ----
    const float inv = 1.0f / l_run;
    const int q = q0w + ln31;
    u16b* orow = O + (size_t)(b * 2048 + q) * 1024 + h * 64;
    #pragma unroll
    for (int rq = 0; rq < 4; ++rq) {
      u16x4 v0, v1;
      #pragma unroll
      for (int j = 0; j < 4; ++j) {
        v0[j] = bfr(oa0[4 * rq + j] * inv);
        v1[j] = bfr(oa1[4 * rq + j] * inv);
      }
      const int d0 = 8 * rq + 4 * hi;
      *(u16x4*)(orow + d0) = v0;
      *(u16x4*)(orow + 32 + d0) = v1;
    }
  }
#undef FSTAGE
}

extern "C" void kernel_launch(void* const* d_in, const int* in_sizes, int n_in,
                              void* d_out, int out_size, void* d_ws, size_t ws_size,
                              hipStream_t stream) {
  const float* x      = (const float*)d_in[0];
  const float* w_attn = (const float*)d_in[1];
  const float* b_attn = (const float*)d_in[2];
  const float* w_proj = (const float*)d_in[3];
  const float* b_proj = (const float*)d_in[4];
  float* out = (float*)d_out;
  char* ws = (char*)d_ws;

  u16b* xb  = (u16b*)(ws + 0);          // [8192][1024] bf16 x; later reused as attn_out
  u16b* waT = (u16b*)(ws + 16777216);   // [3072][1024] w_attn^T bf16
  u16b* wpT = (u16b*)(ws + 23068672);   // [1024][1024] w_proj^T bf16
  u16b* Qb  = (u16b*)(ws + 25165824);   // [64 bh][2048][64]
  u16b* Kb  = (u16b*)(ws + 41943040);
  u16b* Vb  = (u16b*)(ws + 58720256);
  u16b* Vtb = (u16b*)(ws + 75497472);   // [64 bh][64][2048]
  u16b* attn = xb;

  cvt_bf16_kernel<<<2048, 256, 0, stream>>>(x, xb, (8192 * 1024) / 4);
  transpose_cvt_kernel<<<16 * 48, 256, 0, stream>>>(w_attn, waT, 1024, 3072);
  transpose_cvt_kernel<<<16 * 16, 256, 0, stream>>>(w_proj, wpT, 1024, 1024);
  gemm128_kernel<0><<<64 * 24, 256, 0, stream>>>(xb, waT, b_attn, Qb, Kb, Vb, nullptr,
                                                 8192, 3072, 1024);
  transpose_v_kernel<<<64 * 32, 256, 0, stream>>>(Vb, Vtb);
  flash_kernel<<<512, 256, 0, stream>>>(Qb, Kb, Vtb, attn);
  gemm128_kernel<1><<<64 * 8, 256, 0, stream>>>(attn, wpT, b_proj, nullptr, nullptr, nullptr,
                                                out, 8192, 1024, 1024);
}

// Round 6
// 171.921 us; speedup vs baseline: 1.3570x; 1.0484x over previous
//
#include <hip/hip_runtime.h>

// CausalSelfAttention: B=4, T=2048, C=1024, H=16, D=64
// Pipeline: cvt(x,w) -> qkv GEMM (dbuf, XCD-chunked, LDS epilogue; V written transposed)
//           -> flash attn (swapped 32x32, KVBLK=128, merged dual-q-tile sweep, defer-max, dbuf)
//           -> proj GEMM

typedef unsigned short u16b;
typedef __bf16 bf16x8 __attribute__((ext_vector_type(8)));
typedef float f32x4 __attribute__((ext_vector_type(4)));
typedef float f32x16 __attribute__((ext_vector_type(16)));
typedef unsigned short u16x4 __attribute__((ext_vector_type(4)));

#define AS1(p) ((const __attribute__((address_space(1))) void*)(p))
#define AS3(p) ((__attribute__((address_space(3))) void*)(p))
#define GLDS(g, l) __builtin_amdgcn_global_load_lds(AS1(g), AS3(l), 16, 0, 0)

__device__ __forceinline__ u16b bfr(float v) {  // f32 -> bf16 bits, RNE
  union { float f; unsigned u; } x; x.f = v;
  unsigned r = x.u + 0x7fffu + ((x.u >> 16) & 1u);
  return (u16b)(r >> 16);
}

__device__ __forceinline__ unsigned pk2(float lo, float hi) {  // pack 2 f32 -> 2 bf16 in u32
  union { __bf16 h[2]; unsigned u; } t;
  t.h[0] = (__bf16)lo; t.h[1] = (__bf16)hi;
  return t.u;
}

__device__ __forceinline__ float max16(const f32x16& v) {
  float a0 = fmaxf(v[0], v[1]), a1 = fmaxf(v[2], v[3]);
  float a2 = fmaxf(v[4], v[5]), a3 = fmaxf(v[6], v[7]);
  float b0 = fmaxf(v[8], v[9]), b1 = fmaxf(v[10], v[11]);
  float b2 = fmaxf(v[12], v[13]), b3 = fmaxf(v[14], v[15]);
  float c0 = fmaxf(a0, a1), c1 = fmaxf(a2, a3);
  float c2 = fmaxf(b0, b1), c3 = fmaxf(b2, b3);
  return fmaxf(fmaxf(c0, c1), fmaxf(c2, c3));
}

__device__ __forceinline__ float sum16(const f32x16& v) {
  float a0 = v[0] + v[1], a1 = v[2] + v[3], a2 = v[4] + v[5], a3 = v[6] + v[7];
  float b0 = v[8] + v[9], b1 = v[10] + v[11], b2 = v[12] + v[13], b3 = v[14] + v[15];
  float c0 = a0 + a1, c1 = a2 + a3, c2 = b0 + b1, c3 = b2 + b3;
  return (c0 + c1) + (c2 + c3);
}

// ---------------- x (fp32) -> bf16, vectorized ----------------
__global__ __launch_bounds__(256) void cvt_bf16_kernel(
    const float* __restrict__ src, u16b* __restrict__ dst, int n4) {
  int i = blockIdx.x * 256 + threadIdx.x;
  const int stride = gridDim.x * 256;
  for (; i < n4; i += stride) {
    const float4 v = reinterpret_cast<const float4*>(src)[i];
    u16x4 o;
    o[0] = bfr(v.x); o[1] = bfr(v.y); o[2] = bfr(v.z); o[3] = bfr(v.w);
    reinterpret_cast<u16x4*>(dst)[i] = o;
  }
}

// ---------------- weights: src[R][C] fp32 -> dst[C][R] bf16 (transpose) ----------------
__global__ __launch_bounds__(256) void transpose_cvt_kernel(
    const float* __restrict__ src, u16b* __restrict__ dst, int R, int C) {
  __shared__ u16b tile[64][72];
  const int nc = C >> 6;
  const int br = blockIdx.x / nc, bc = blockIdx.x % nc;
  const int r0 = br << 6, c0 = bc << 6;
  const int c = threadIdx.x & 63, r4 = threadIdx.x >> 6;
  #pragma unroll
  for (int i = 0; i < 16; ++i) {
    const int r = r4 + 4 * i;
    tile[r][c] = bfr(src[(size_t)(r0 + r) * C + c0 + c]);
  }
  __syncthreads();
  #pragma unroll
  for (int i = 0; i < 16; ++i) {
    const int rr = r4 + 4 * i;
    dst[(size_t)(c0 + rr) * R + r0 + c] = tile[c][rr];
  }
}

// ---------------- 128x128 tile bf16 GEMM: dbuf counted-vmcnt + XCD chunking ----------------
// EPI==0: Q(scaled)/K as [B,H,T,D] bf16; V written TRANSPOSED as Vt [bh][64 d][2048 t]
// EPI==1: fp32 out [M][N]
template <int EPI>
__global__ __launch_bounds__(256, 2) void gemm128_kernel(
    const u16b* __restrict__ A, const u16b* __restrict__ Bt,
    const float* __restrict__ bias,
    u16b* __restrict__ oQ, u16b* __restrict__ oK, u16b* __restrict__ oVt,
    float* __restrict__ oF, int M, int N, int K) {
  __shared__ u16b smem[16384];  // 2 buf x (As 8KB + Bs 8KB); epilogue reuses all 32KB
  const int tid = threadIdx.x;
  const int wid = tid >> 6, lane = tid & 63;
  const int nb = N >> 7;
  const int lin = (blockIdx.x & 7) * ((int)gridDim.x >> 3) + (blockIdx.x >> 3);
  const int brow = lin / nb, bcol = lin % nb;
  const int wr = (wid >> 1) << 6, wc = (wid & 1) << 6;

  f32x4 acc[4][4] = {};

  const int ar = (wid << 4) + (lane >> 2);
  const int ac = (lane & 3) << 3;
  const u16b* Ab = A + (size_t)((brow << 7) + ar) * K + ac;
  const u16b* Bb = Bt + (size_t)((bcol << 7) + ar) * K + ac;
  const int fr = lane & 15;
  const int fk = (lane >> 4) << 3;
  const int nk = K >> 5;

#define STAGE(bufi, kk)                                                        \
  {                                                                            \
    char* sb = (char*)smem + (bufi) * 16384;                                   \
    GLDS(Ab + (kk),                  sb + wid * 1024);                         \
    GLDS(Ab + (size_t)64 * K + (kk), sb + 4096 + wid * 1024);                  \
    GLDS(Bb + (kk),                  sb + 8192 + wid * 1024);                  \
    GLDS(Bb + (size_t)64 * K + (kk), sb + 12288 + wid * 1024);                 \
  }

  STAGE(0, 0);
  STAGE(1, 32);

  #pragma unroll 1
  for (int kt = 0; kt < nk; ++kt) {
    if (kt + 1 < nk) asm volatile("s_waitcnt vmcnt(4)" ::: "memory");
    else             asm volatile("s_waitcnt vmcnt(0)" ::: "memory");
    __builtin_amdgcn_s_barrier();

    const u16b* As = (const u16b*)((const char*)smem + (kt & 1) * 16384);
    const u16b* Bs = As + 4096;
    bf16x8 af[4], bfv[4];
    #pragma unroll
    for (int i = 0; i < 4; ++i)
      af[i] = *(const bf16x8*)&As[(wr + i * 16 + fr) * 32 + fk];
    #pragma unroll
    for (int j = 0; j < 4; ++j)
      bfv[j] = *(const bf16x8*)&Bs[(wc + j * 16 + fr) * 32 + fk];
    __builtin_amdgcn_s_setprio(1);
    #pragma unroll
    for (int i = 0; i < 4; ++i)
      #pragma unroll
      for (int j = 0; j < 4; ++j)
        acc[i][j] = __builtin_amdgcn_mfma_f32_16x16x32_bf16(af[i], bfv[j], acc[i][j], 0, 0, 0);
    __builtin_amdgcn_s_setprio(0);

    __builtin_amdgcn_s_barrier();
    if (kt + 2 < nk) STAGE(kt & 1, (kt + 2) << 5);
  }
#undef STAGE

  const int fq = lane >> 4;
  if (EPI == 1) {
    #pragma unroll
    for (int j = 0; j < 4; ++j) {
      const int n0 = (bcol << 7) + wc + j * 16 + fr;
      const float bv = bias[n0];
      #pragma unroll
      for (int i = 0; i < 4; ++i) {
        #pragma unroll
        for (int r = 0; r < 4; ++r) {
          const int m0 = (brow << 7) + wr + i * 16 + fq * 4 + r;
          oF[(size_t)m0 * N + n0] = acc[i][j][r] + bv;
        }
      }
    }
  } else {
    const int sect = bcol >> 3;  // 0:Q 1:K 2:V (block-uniform)
    if (sect < 2) {
      // Q/K: LDS tile [m 128][n 128] swizzled, then coalesced [B,H,T,D] stores
      const float qs = (sect == 0) ? 0.1803368801f : 1.0f;  // 1/sqrt(64)*log2(e) in Q
      u16b* oPtr = (sect == 0) ? oQ : oK;
      u16b* tile = (u16b*)smem;
      #pragma unroll
      for (int j = 0; j < 4; ++j) {
        const int n = wc + j * 16 + fr;
        const float bv = bias[(bcol << 7) + n];
        #pragma unroll
        for (int i = 0; i < 4; ++i) {
          #pragma unroll
          for (int r = 0; r < 4; ++r) {
            const int m = wr + i * 16 + fq * 4 + r;
            const int byteoff = m * 256 + (((n >> 3) ^ (m & 7)) << 4) + ((n & 7) << 1);
            *(u16b*)((char*)tile + byteoff) = bfr((acc[i][j][r] + bv) * qs);
          }
        }
      }
      __syncthreads();
      const int nh = wid >> 1;
      const int c = lane & 7;
      #pragma unroll
      for (int it = 0; it < 8; ++it) {
        const int m = ((wid & 1) << 6) + (it << 3) + (lane >> 3);
        const int chunk = (nh << 3) + (c ^ (m & 7));
        const bf16x8 val = *(const bf16x8*)((const char*)tile + m * 256 + chunk * 16);
        const int m0 = (brow << 7) + m;
        const int n0 = (bcol << 7) + (nh << 6) + (c << 3);
        const int bb = m0 >> 11, tt = m0 & 2047;
        const int h = (n0 >> 6) & 15, d = n0 & 63;
        *(bf16x8*)(oPtr + (((size_t)(bb * 16 + h) * 2048 + tt) * 64 + d)) = val;
      }
    } else {
      // V: LDS tile TRANSPOSED [nl 128][m 128] swizzled, store Vt[bh][d][t] rows
      u16b* tile = (u16b*)smem;
      #pragma unroll
      for (int j = 0; j < 4; ++j) {
        const int nl = wc + j * 16 + fr;
        const float bv = bias[(bcol << 7) + nl];
        #pragma unroll
        for (int i = 0; i < 4; ++i) {
          #pragma unroll
          for (int r = 0; r < 4; ++r) {
            const int m = wr + i * 16 + fq * 4 + r;
            const int byteoff = nl * 256 + (((m >> 3) ^ (nl & 7)) << 4) + ((m & 7) << 1);
            *(u16b*)((char*)tile + byteoff) = bfr(acc[i][j][r] + bv);
          }
        }
      }
      __syncthreads();
      const int row0 = wid << 5;   // wave's 32 nl-rows
      const int c16 = lane & 15;   // 16B chunk within 256B row
      const int rr = lane >> 4;    // row offset 0..3
      const int t0 = (brow << 7) & 2047;
      const int bb = brow >> 4;
      #pragma unroll
      for (int it = 0; it < 8; ++it) {
        const int nl = row0 + (it << 2) + rr;
        const int pch = c16 ^ (nl & 7);
        const bf16x8 val = *(const bf16x8*)((const char*)tile + nl * 256 + pch * 16);
        const int h = ((bcol & 7) << 1) + (nl >> 6);
        const int d = nl & 63;
        *(bf16x8*)(oVt + ((size_t)((bb << 4) + h) * 64 + d) * 2048 + t0 + (c16 << 3)) = val;
      }
    }
  }
}

// ---------------- flash attention: swapped 32x32, KVBLK=128, merged dual-tile sweep ----------------
// grid = 512: bid = dp*64 + bh (bh fastest -> bh pinned to XCD bh%8).
// Block p owns q-tiles g1=p and g2=15-p; ONE kv sweep kt=0..g2 serves both (tile1 while kt<=g1).
// dp->p remap pairs heavy+light blocks per CU: (16-p)+(9+p)=25 iters for every CU pair.
// LDS per buffer: K [128 t][128B swz] 16KB + V [64 d][256B swz] 16KB; dbuf = 64KB.
__global__ __launch_bounds__(256, 2) void flash_kernel(
    const u16b* __restrict__ Q, const u16b* __restrict__ K,
    const u16b* __restrict__ Vt, u16b* __restrict__ O) {
  __shared__ u16b smem[32768];  // 64KB
  const int bid = blockIdx.x;
  const int bh = bid & 63;
  const int dp = bid >> 6;                    // dispatch slot 0..7
  const int p = (dp < 4) ? dp : (11 - dp);    // pair (0,7),(1,6),(2,5),(3,4)
  const int g1 = p, g2 = 15 - p;
  const int tid = threadIdx.x, wid = tid >> 6, lane = tid & 63;
  const int ln31 = lane & 31, hi = lane >> 5;
  const int l7 = ln31 & 7;
  const size_t baseQK = (size_t)bh * 2048 * 64;
  const size_t baseV = (size_t)bh * 64 * 2048;
  const int b = bh >> 4, h = bh & 15;
  const int rk = lane >> 3;
  const int sk = ((lane & 7) ^ rk) << 3;
  const int rv = lane >> 4;
  const int cv = lane & 15;

#define FSTAGE(kt, bi)                                                         \
  {                                                                            \
    char* kb_ = (char*)smem + (bi) * 32768;                                    \
    char* vb_ = kb_ + 16384;                                                   \
    const int k0_ = (kt) << 7;                                                 \
    _Pragma("unroll")                                                          \
    for (int c = 0; c < 4; ++c) {                                              \
      const int i = 4 * wid + c;                                               \
      const int r = 8 * i + rk;                                                \
      GLDS(K + baseQK + (size_t)(k0_ + r) * 64 + sk, kb_ + i * 1024);          \
    }                                                                          \
    _Pragma("unroll")                                                          \
    for (int c = 0; c < 4; ++c) {                                              \
      const int i = 4 * wid + c;                                               \
      const int r = 4 * i + rv;                                                \
      const int scv = (cv ^ (r & 7)) << 3;                                     \
      GLDS(Vt + baseV + (size_t)r * 2048 + k0_ + scv, vb_ + i * 1024);         \
    }                                                                          \
  }

  const int q0wA = (g1 << 7) + wid * 32;
  const int q0wB = (g2 << 7) + wid * 32;

  bf16x8 qfA[4], qfB[4];
  {
    const u16b* qpA = Q + baseQK + (size_t)(q0wA + ln31) * 64 + hi * 8;
    const u16b* qpB = Q + baseQK + (size_t)(q0wB + ln31) * 64 + hi * 8;
    #pragma unroll
    for (int kk = 0; kk < 4; ++kk) {
      qfA[kk] = *(const bf16x8*)(qpA + kk * 16);
      qfB[kk] = *(const bf16x8*)(qpB + kk * 16);
    }
  }

  float mA = -3e38f, lA = 0.f, mB = -3e38f, lB = 0.f;
  f32x16 oaA0 = {}, oaA1 = {}, oaB0 = {}, oaB1 = {};

  FSTAGE(0, 0);
  FSTAGE(1, 1);

  #pragma unroll 1
  for (int kt = 0; kt <= g2; ++kt) {
    if (kt < g2) asm volatile("s_waitcnt vmcnt(8)" ::: "memory");
    else         asm volatile("s_waitcnt vmcnt(0)" ::: "memory");
    __builtin_amdgcn_s_barrier();

    const char* kb = (const char*)smem + (kt & 1) * 32768;
    const char* vb = kb + 16384;

    auto compute_tile = [&](const bf16x8* qf, float& m_run, float& l_run,
                            f32x16& oa0, f32x16& oa1, const int gq) {
      const bool diag = (kt == gq);
      const int maxsub = diag ? wid : 3;  // wave-uniform

      f32x16 s[4] = {};
      __builtin_amdgcn_s_setprio(1);
      #pragma unroll
      for (int ss = 0; ss < 4; ++ss) {
        if (ss <= maxsub) {
          const int row = 32 * ss + ln31;
          #pragma unroll
          for (int kk = 0; kk < 4; ++kk) {
            const int ch = (2 * kk + hi) ^ l7;
            const bf16x8 kf = *(const bf16x8*)(kb + row * 128 + ch * 16);
            s[ss] = __builtin_amdgcn_mfma_f32_32x32x16_bf16(kf, qf[kk], s[ss], 0, 0, 0);
          }
        }
      }
      __builtin_amdgcn_s_setprio(0);

      if (diag) {
        #pragma unroll
        for (int ss = 0; ss < 4; ++ss) {
          if (ss == wid) {
            #pragma unroll
            for (int r = 0; r < 16; ++r) {
              const int kvr = (r & 3) + 8 * (r >> 2) + 4 * hi;
              if (kvr > ln31) s[ss][r] = -3e38f;
            }
          }
        }
      }

      float tm = -3e38f;
      #pragma unroll
      for (int ss = 0; ss < 4; ++ss)
        if (ss <= maxsub) tm = fmaxf(tm, max16(s[ss]));
      tm = fmaxf(tm, __shfl_xor(tm, 32));

      if (!__all(tm <= m_run + 8.f)) {
        const float mnew = fmaxf(m_run, tm);
        const float scale = __builtin_amdgcn_exp2f(m_run - mnew);
        m_run = mnew;
        l_run *= scale;
        #pragma unroll
        for (int r = 0; r < 16; ++r) { oa0[r] *= scale; oa1[r] *= scale; }
      }

      float rs = 0.f;
      #pragma unroll
      for (int ss = 0; ss < 4; ++ss) {
        if (ss <= maxsub) {
          #pragma unroll
          for (int r = 0; r < 16; ++r)
            s[ss][r] = __builtin_amdgcn_exp2f(s[ss][r] - m_run);
          rs += sum16(s[ss]);
        }
      }
      rs += __shfl_xor(rs, 32);
      l_run += rs;

      union WB { unsigned u[4]; bf16x8 v; };
      __builtin_amdgcn_s_setprio(1);
      #pragma unroll
      for (int ss = 0; ss < 4; ++ss) {
        if (ss <= maxsub) {
          WB pA, pB;
#define MKPA(W0, W1, W2, W3, P0, P1, P2, P3, P4, P5, P6, P7)                 \
          {                                                                   \
            unsigned a0 = pk2(P0, P1), a1 = pk2(P2, P3);                      \
            unsigned b0 = pk2(P4, P5), b1 = pk2(P6, P7);                      \
            auto r0 = __builtin_amdgcn_permlane32_swap(a0, b0, false, false); \
            auto r1 = __builtin_amdgcn_permlane32_swap(a1, b1, false, false); \
            unsigned o0[2], o1[2];                                            \
            __builtin_memcpy(o0, &r0, 8); __builtin_memcpy(o1, &r1, 8);       \
            W0 = o0[0]; W2 = o0[1]; W1 = o1[0]; W3 = o1[1];                   \
          }
          MKPA(pA.u[0], pA.u[1], pA.u[2], pA.u[3],
               s[ss][0], s[ss][1], s[ss][2], s[ss][3],
               s[ss][4], s[ss][5], s[ss][6], s[ss][7]);
          MKPA(pB.u[0], pB.u[1], pB.u[2], pB.u[3],
               s[ss][8], s[ss][9], s[ss][10], s[ss][11],
               s[ss][12], s[ss][13], s[ss][14], s[ss][15]);
#undef MKPA
          const int cxa = ((4 * ss + hi) ^ l7) << 4;
          const int cxb = ((4 * ss + 2 + hi) ^ l7) << 4;
          const char* v0 = vb + ln31 * 256;
          const char* v1 = vb + (32 + ln31) * 256;
          oa0 = __builtin_amdgcn_mfma_f32_32x32x16_bf16(*(const bf16x8*)(v0 + cxa), pA.v, oa0, 0, 0, 0);
          oa1 = __builtin_amdgcn_mfma_f32_32x32x16_bf16(*(const bf16x8*)(v1 + cxa), pA.v, oa1, 0, 0, 0);
          oa0 = __builtin_amdgcn_mfma_f32_32x32x16_bf16(*(const bf16x8*)(v0 + cxb), pB.v, oa0, 0, 0, 0);
          oa1 = __builtin_amdgcn_mfma_f32_32x32x16_bf16(*(const bf16x8*)(v1 + cxb), pB.v, oa1, 0, 0, 0);
        }
      }
      __builtin_amdgcn_s_setprio(0);
    };

    compute_tile(qfB, mB, lB, oaB0, oaB1, g2);
    if (kt <= g1) compute_tile(qfA, mA, lA, oaA0, oaA1, g1);

    __builtin_amdgcn_s_barrier();
    if (kt + 2 <= g2) FSTAGE(kt + 2, kt & 1);
  }

  // ---- epilogues: lane owns output rows q0w{A,B}+ln31 ----
  {
    const float inv = 1.0f / lA;
    const int q = q0wA + ln31;
    u16b* orow = O + (size_t)(b * 2048 + q) * 1024 + h * 64;
    #pragma unroll
    for (int rq = 0; rq < 4; ++rq) {
      u16x4 v0, v1;
      #pragma unroll
      for (int j = 0; j < 4; ++j) {
        v0[j] = bfr(oaA0[4 * rq + j] * inv);
        v1[j] = bfr(oaA1[4 * rq + j] * inv);
      }
      const int d0 = 8 * rq + 4 * hi;
      *(u16x4*)(orow + d0) = v0;
      *(u16x4*)(orow + 32 + d0) = v1;
    }
  }
  {
    const float inv = 1.0f / lB;
    const int q = q0wB + ln31;
    u16b* orow = O + (size_t)(b * 2048 + q) * 1024 + h * 64;
    #pragma unroll
    for (int rq = 0; rq < 4; ++rq) {
      u16x4 v0, v1;
      #pragma unroll
      for (int j = 0; j < 4; ++j) {
        v0[j] = bfr(oaB0[4 * rq + j] * inv);
        v1[j] = bfr(oaB1[4 * rq + j] * inv);
      }
      const int d0 = 8 * rq + 4 * hi;
      *(u16x4*)(orow + d0) = v0;
      *(u16x4*)(orow + 32 + d0) = v1;
    }
  }
#undef FSTAGE
}

extern "C" void kernel_launch(void* const* d_in, const int* in_sizes, int n_in,
                              void* d_out, int out_size, void* d_ws, size_t ws_size,
                              hipStream_t stream) {
  const float* x      = (const float*)d_in[0];
  const float* w_attn = (const float*)d_in[1];
  const float* b_attn = (const float*)d_in[2];
  const float* w_proj = (const float*)d_in[3];
  const float* b_proj = (const float*)d_in[4];
  float* out = (float*)d_out;
  char* ws = (char*)d_ws;

  u16b* xb  = (u16b*)(ws + 0);          // [8192][1024] bf16 x; later reused as attn_out
  u16b* waT = (u16b*)(ws + 16777216);   // [3072][1024] w_attn^T bf16
  u16b* wpT = (u16b*)(ws + 23068672);   // [1024][1024] w_proj^T bf16
  u16b* Qb  = (u16b*)(ws + 25165824);   // [64 bh][2048][64]
  u16b* Kb  = (u16b*)(ws + 41943040);
  u16b* Vtb = (u16b*)(ws + 75497472);   // [64 bh][64][2048] (written directly by qkv GEMM)
  u16b* attn = xb;

  cvt_bf16_kernel<<<2048, 256, 0, stream>>>(x, xb, (8192 * 1024) / 4);
  transpose_cvt_kernel<<<16 * 48, 256, 0, stream>>>(w_attn, waT, 1024, 3072);
  transpose_cvt_kernel<<<16 * 16, 256, 0, stream>>>(w_proj, wpT, 1024, 1024);
  gemm128_kernel<0><<<64 * 24, 256, 0, stream>>>(xb, waT, b_attn, Qb, Kb, Vtb, nullptr,
                                                 8192, 3072, 1024);
  flash_kernel<<<512, 256, 0, stream>>>(Qb, Kb, Vtb, attn);
  gemm128_kernel<1><<<64 * 8, 256, 0, stream>>>(attn, wpT, b_proj, nullptr, nullptr, nullptr,
                                                out, 8192, 1024, 1024);
}